// Round 3
// baseline (1104.455 us; speedup 1.0000x reference)
//
#include <hip/hip_runtime.h>
#include <hip/hip_fp16.h>

// ---------------- degree / dinv ----------------
__global__ void k_deg(const int* __restrict__ dst, int E, int N, int* __restrict__ cnt) {
    int e = blockIdx.x * blockDim.x + threadIdx.x;
    if (e < E) {
        int d = dst[e];
        if ((unsigned)d < (unsigned)N) atomicAdd(&cnt[d], 1);
    }
}

__global__ void k_dinv(const int* __restrict__ cnt, int N, float* __restrict__ dinv) {
    int n = blockIdx.x * blockDim.x + threadIdx.x;
    if (n < N) dinv[n] = rsqrtf((float)(cnt[n] + 1));  // +1 self-loop; deg>=1 always
}

// ---------------- exclusive scan of cnt -> offs (2048 items/block) ----------------
__global__ void k_scan1(const int* __restrict__ cnt, int N,
                        int* __restrict__ offs, int* __restrict__ bsums) {
    __shared__ int sd[256];
    int t = threadIdx.x;
    int base = blockIdx.x * 2048 + t * 8;
    int v[8];
    int s = 0;
#pragma unroll
    for (int j = 0; j < 8; j++) {
        int i = base + j;
        v[j] = (i < N) ? cnt[i] : 0;
        s += v[j];
    }
    sd[t] = s;
    __syncthreads();
    for (int off = 1; off < 256; off <<= 1) {
        int x = (t >= off) ? sd[t - off] : 0;
        __syncthreads();
        sd[t] += x;
        __syncthreads();
    }
    int excl = (t == 0) ? 0 : sd[t - 1];
    if (t == 255) bsums[blockIdx.x] = sd[255];
    int run = excl;
#pragma unroll
    for (int j = 0; j < 8; j++) {
        int i = base + j;
        if (i < N) offs[i] = run;
        run += v[j];
    }
}

__global__ void k_scan2(int* __restrict__ bsums, int nb) {  // nb <= 64, one wave
    int t = threadIdx.x;
    int v = (t < nb) ? bsums[t] : 0;
    int orig = v;
    for (int off = 1; off < 64; off <<= 1) {
        int y = __shfl_up(v, off);
        if (t >= off) v += y;
    }
    if (t < nb) bsums[t] = v - orig;  // exclusive
}

__global__ void k_scan3(int* __restrict__ offs, int N, const int* __restrict__ bsums) {
    int i = blockIdx.x * blockDim.x + threadIdx.x;
    if (i < N) offs[i] += bsums[i >> 11];
}

// ---------------- CSR scatter (by dst, storing src) ----------------
__global__ void k_scatter(const int* __restrict__ src, const int* __restrict__ dst, int E, int N,
                          const int* __restrict__ offs, int* __restrict__ cursor,
                          int* __restrict__ csr) {
    int e = blockIdx.x * blockDim.x + threadIdx.x;
    if (e < E) {
        int d = dst[e];
        if ((unsigned)d < (unsigned)N) {
            int p = atomicAdd(&cursor[d], 1);
            csr[offs[d] + p] = src[e];
        }
    }
}

// ---------------- fused: gather-aggregate X -> branch MLP (elu) -> Z = h_fused @ Wf ----------------
// wave-per-node (grid-stride); lane l holds feature dim l throughout.
// LDS: Wn fp32 16KB + Ws fp32 16KB + Wf fp16-pairs 32KB = 64KB exactly.
__global__ __launch_bounds__(512) void k_fused(
        const float* __restrict__ X, const float* __restrict__ dinv,
        const int* __restrict__ offs, const int* __restrict__ cnt,
        const int* __restrict__ csr,
        const float* __restrict__ Wn, const float* __restrict__ bn,
        const float* __restrict__ Ws, const float* __restrict__ bs,
        const float* __restrict__ Wf, int N, __half* __restrict__ Z) {
    __shared__ float sWn[32 * 128];      // sWn[i*128 + j] = Wn[i][j]
    __shared__ float sWs[32 * 128];
    __shared__ __half2 sWf2[128 * 64];   // sWf2[m2*64 + l] = (Wf[2m2][l], Wf[2m2+1][l])
    for (int idx = threadIdx.x; idx < 32 * 128; idx += blockDim.x) {
        sWn[idx] = Wn[idx];
        sWs[idx] = Ws[idx];
    }
    for (int idx = threadIdx.x; idx < 128 * 64; idx += blockDim.x) {
        int m2 = idx >> 6, l = idx & 63;
        sWf2[idx] = __floats2half2_rn(Wf[(2 * m2) * 64 + l], Wf[(2 * m2 + 1) * 64 + l]);
    }
    __syncthreads();

    int l = threadIdx.x & 63;
    int wpb = blockDim.x >> 6;
    int gw = blockIdx.x * wpb + (threadIdx.x >> 6);
    int nw = gridDim.x * wpb;
    float bn0 = bn[l], bn1 = bn[64 + l];
    float bs0 = bs[l], bs1 = bs[64 + l];

    for (int n = gw; n < N; n += nw) {
        // ---- layer-1 aggregation: t[l] = sum_{s->n} dinv[s]*dinv[n]*X[s][l] + self-loop
        float dn = dinv[n];
        float t = dn * dn * X[(size_t)n * 64 + l];
        int base = offs[n], c = cnt[n];
        for (int j0 = 0; j0 < c; j0 += 64) {
            int idx = j0 + l;
            int s = 0;
            float ds = 0.f;
            if (idx < c) {
                int s0 = csr[base + idx];
                s = ((unsigned)s0 < (unsigned)N) ? s0 : 0;  // clamp: garbage -> finite
                ds = dinv[s];
            }
            int m = min(64, c - j0);
            for (int j = 0; j < m; j++) {
                int sj = __shfl(s, j);
                float wj = __shfl(ds, j) * dn;
                t += wj * X[(size_t)sj * 64 + l];
            }
        }
        // ---- branch GEMMs: h_nuc = t[0:32]@Wn + bn ; h_surf = t[32:64]@Ws + bs
        // lane l accumulates h_nuc[l] (h0), h_nuc[64+l] (h1), h_surf[l] (h2), h_surf[64+l] (h3)
        float h0 = bn0, h1 = bn1, h2 = bs0, h3 = bs1;
#pragma unroll
        for (int i = 0; i < 32; i++) {
            float a = __shfl(t, i);
            float cc = __shfl(t, 32 + i);
            h0 = fmaf(a, sWn[i * 128 + l], h0);
            h1 = fmaf(a, sWn[i * 128 + 64 + l], h1);
            h2 = fmaf(cc, sWs[i * 128 + l], h2);
            h3 = fmaf(cc, sWs[i * 128 + 64 + l], h3);
        }
        h0 = h0 > 0.f ? h0 : expm1f(h0);
        h1 = h1 > 0.f ? h1 : expm1f(h1);
        h2 = h2 > 0.f ? h2 : expm1f(h2);
        h3 = h3 > 0.f ? h3 : expm1f(h3);
        // ---- Z[l] = sum_{m=0}^{255} h_fused[m] * Wf[m][l]
        // h_fused[0..63]=h0 lanes, [64..127]=h1, [128..191]=h2, [192..255]=h3
        float y = 0.f;
#pragma unroll 8
        for (int j2 = 0; j2 < 32; j2++) {
            __half2 u0 = sWf2[(j2) * 64 + l];        // Wf rows 2j2, 2j2+1
            __half2 u1 = sWf2[(32 + j2) * 64 + l];   // rows 64+2j2, 64+2j2+1
            __half2 u2 = sWf2[(64 + j2) * 64 + l];   // rows 128+...
            __half2 u3 = sWf2[(96 + j2) * 64 + l];   // rows 192+...
            y = fmaf(__shfl(h0, 2 * j2), __low2float(u0), y);
            y = fmaf(__shfl(h0, 2 * j2 + 1), __high2float(u0), y);
            y = fmaf(__shfl(h1, 2 * j2), __low2float(u1), y);
            y = fmaf(__shfl(h1, 2 * j2 + 1), __high2float(u1), y);
            y = fmaf(__shfl(h2, 2 * j2), __low2float(u2), y);
            y = fmaf(__shfl(h2, 2 * j2 + 1), __high2float(u2), y);
            y = fmaf(__shfl(h3, 2 * j2), __low2float(u3), y);
            y = fmaf(__shfl(h3, 2 * j2 + 1), __high2float(u3), y);
        }
        Z[(size_t)n * 64 + l] = __float2half_rn(y);
    }
}

// ---------------- layer-2 aggregation + bias + softmax ----------------
__global__ __launch_bounds__(256) void k_agg_softmax(
        const __half* __restrict__ Z, const float* __restrict__ dinv,
        const int* __restrict__ offs, const int* __restrict__ cnt,
        const int* __restrict__ csr, const float* __restrict__ bf_,
        int N, float* __restrict__ out) {
    int w = blockIdx.x * (blockDim.x >> 6) + (threadIdx.x >> 6);
    int l = threadIdx.x & 63;
    if (w >= N) return;
    float dn = dinv[w];
    float acc = dn * dn * __half2float(Z[(size_t)w * 64 + l]);
    int base = offs[w], c = cnt[w];
    for (int j0 = 0; j0 < c; j0 += 64) {
        int idx = j0 + l;
        int s = 0;
        float ds = 0.f;
        if (idx < c) {
            int s0 = csr[base + idx];
            s = ((unsigned)s0 < (unsigned)N) ? s0 : 0;  // clamp: garbage -> finite
            ds = dinv[s];
        }
        int m = min(64, c - j0);
        for (int j = 0; j < m; j++) {
            int sj = __shfl(s, j);
            float wj = __shfl(ds, j) * dn;
            acc += wj * __half2float(Z[(size_t)sj * 64 + l]);
        }
    }
    acc += bf_[l];
    // softmax over 64 lanes
    float mx = acc;
    for (int o = 32; o >= 1; o >>= 1) mx = fmaxf(mx, __shfl_xor(mx, o));
    float e = expf(acc - mx);
    float sm = e;
    for (int o = 32; o >= 1; o >>= 1) sm += __shfl_xor(sm, o);
    out[(size_t)w * 64 + l] = e / sm;
}

extern "C" void kernel_launch(void* const* d_in, const int* in_sizes, int n_in,
                              void* d_out, int out_size, void* d_ws, size_t ws_size,
                              hipStream_t stream) {
    const float* X = (const float*)d_in[0];
    const int* ei = (const int*)d_in[1];
    // d_in[2] = batch (unused)
    const float* Wn = (const float*)d_in[3];
    const float* bn = (const float*)d_in[4];
    const float* Ws = (const float*)d_in[5];
    const float* bs = (const float*)d_in[6];
    const float* Wf = (const float*)d_in[7];
    const float* bfu = (const float*)d_in[8];

    const int N = in_sizes[2];        // 100000
    const int E = in_sizes[1] / 2;    // 1600000
    const int* src = ei;
    const int* dst = ei + E;

    // workspace layout (128-aligned); total ~20.8 MB
    char* ws = (char*)d_ws;
    int* cnt      = (int*)(ws + 0);            // 400000 B (pad -> 400128)
    int* cursor   = (int*)(ws + 400128);       // 400000 B (pad -> 800256)
    float* dinv   = (float*)(ws + 800256);     // 400000 B (pad -> 1200384)
    int* offs     = (int*)(ws + 1200384);      // 400000 B (pad -> 1600512)
    int* bsums    = (int*)(ws + 1600512);      // 256 B
    int* csr      = (int*)(ws + 1600768);      // 6400000 B -> 8000768
    __half* Z     = (__half*)(ws + 8000768);   // 12800000 B -> 20800768 total

    hipMemsetAsync(ws, 0, 800256, stream);  // zero cnt + cursor

    int ebl = (E + 255) / 256;
    int nbl = (N + 255) / 256;
    int nb1 = (N + 2047) / 2048;  // 49 <= 64

    k_deg<<<ebl, 256, 0, stream>>>(dst, E, N, cnt);
    k_dinv<<<nbl, 256, 0, stream>>>(cnt, N, dinv);
    k_scan1<<<nb1, 256, 0, stream>>>(cnt, N, offs, bsums);
    k_scan2<<<1, 64, 0, stream>>>(bsums, nb1);
    k_scan3<<<nbl, 256, 0, stream>>>(offs, N, bsums);
    k_scatter<<<ebl, 256, 0, stream>>>(src, dst, E, N, offs, cursor, csr);

    // persistent fused kernel: 512 blocks x 512 thr (8 waves), 64KB LDS -> 2 blocks/CU
    k_fused<<<512, 512, 0, stream>>>(X, dinv, offs, cnt, csr, Wn, bn, Ws, bs, Wf, N, Z);

    int wbl = (N + 3) / 4;  // 4 waves/block
    k_agg_softmax<<<wbl, 256, 0, stream>>>(Z, dinv, offs, cnt, csr, bfu, N, (float*)d_out);
}

// Round 4
// 870.240 us; speedup vs baseline: 1.2691x; 1.2691x over previous
//
#include <hip/hip_runtime.h>
#include <hip/hip_fp16.h>

// ---------------- degree / dinv ----------------
__global__ void k_deg(const int* __restrict__ dst, int E, int N, int* __restrict__ cnt) {
    int e = blockIdx.x * blockDim.x + threadIdx.x;
    if (e < E) {
        int d = dst[e];
        if ((unsigned)d < (unsigned)N) atomicAdd(&cnt[d], 1);
    }
}

__global__ void k_dinv(const int* __restrict__ cnt, int N, float* __restrict__ dinv) {
    int n = blockIdx.x * blockDim.x + threadIdx.x;
    if (n < N) dinv[n] = rsqrtf((float)(cnt[n] + 1));  // +1 self-loop; deg>=1 always
}

// ---------------- exclusive scan of cnt -> offs (2048 items/block) ----------------
__global__ void k_scan1(const int* __restrict__ cnt, int N,
                        int* __restrict__ offs, int* __restrict__ bsums) {
    __shared__ int sd[256];
    int t = threadIdx.x;
    int base = blockIdx.x * 2048 + t * 8;
    int v[8];
    int s = 0;
#pragma unroll
    for (int j = 0; j < 8; j++) {
        int i = base + j;
        v[j] = (i < N) ? cnt[i] : 0;
        s += v[j];
    }
    sd[t] = s;
    __syncthreads();
    for (int off = 1; off < 256; off <<= 1) {
        int x = (t >= off) ? sd[t - off] : 0;
        __syncthreads();
        sd[t] += x;
        __syncthreads();
    }
    int excl = (t == 0) ? 0 : sd[t - 1];
    if (t == 255) bsums[blockIdx.x] = sd[255];
    int run = excl;
#pragma unroll
    for (int j = 0; j < 8; j++) {
        int i = base + j;
        if (i < N) offs[i] = run;
        run += v[j];
    }
}

__global__ void k_scan2(int* __restrict__ bsums, int nb) {  // nb <= 64, one wave
    int t = threadIdx.x;
    int v = (t < nb) ? bsums[t] : 0;
    int orig = v;
    for (int off = 1; off < 64; off <<= 1) {
        int y = __shfl_up(v, off);
        if (t >= off) v += y;
    }
    if (t < nb) bsums[t] = v - orig;  // exclusive
}

__global__ void k_scan3(int* __restrict__ offs, int N, const int* __restrict__ bsums) {
    int i = blockIdx.x * blockDim.x + threadIdx.x;
    if (i < N) offs[i] += bsums[i >> 11];
}

// ---------------- CSR scatter (by dst, storing src) ----------------
__global__ void k_scatter(const int* __restrict__ src, const int* __restrict__ dst, int E, int N,
                          const int* __restrict__ offs, int* __restrict__ cursor,
                          int* __restrict__ csr) {
    int e = blockIdx.x * blockDim.x + threadIdx.x;
    if (e < E) {
        int d = dst[e];
        if ((unsigned)d < (unsigned)N) {
            int p = atomicAdd(&cursor[d], 1);
            csr[offs[d] + p] = src[e];
        }
    }
}

// ---------------- layer-1 aggregation: aggX[n] = dinv[n]*X[n] + sum_s dinv[s]*X[s] ----------------
// thread = (node, float4 chunk); 16 threads per node; unroll-4 neighbor loop for MLP.
__global__ __launch_bounds__(256) void k_agg1(
        const float4* __restrict__ X4, const float* __restrict__ dinv,
        const int* __restrict__ offs, const int* __restrict__ cnt,
        const int* __restrict__ csr, int N, float4* __restrict__ aggX4) {
    int tid = blockIdx.x * blockDim.x + threadIdx.x;
    int n = tid >> 4;
    int f = tid & 15;
    if (n >= N) return;
    float4 x = X4[(size_t)n * 16 + f];
    float w = dinv[n];
    float4 acc = make_float4(w * x.x, w * x.y, w * x.z, w * x.w);
    int base = offs[n], deg = cnt[n];
    int j = 0;
    for (; j + 4 <= deg; j += 4) {
        int s0 = csr[base + j];
        int s1 = csr[base + j + 1];
        int s2 = csr[base + j + 2];
        int s3 = csr[base + j + 3];
        s0 = ((unsigned)s0 < (unsigned)N) ? s0 : 0;
        s1 = ((unsigned)s1 < (unsigned)N) ? s1 : 0;
        s2 = ((unsigned)s2 < (unsigned)N) ? s2 : 0;
        s3 = ((unsigned)s3 < (unsigned)N) ? s3 : 0;
        float w0 = dinv[s0], w1 = dinv[s1], w2 = dinv[s2], w3 = dinv[s3];
        float4 a = X4[(size_t)s0 * 16 + f];
        float4 b = X4[(size_t)s1 * 16 + f];
        float4 c = X4[(size_t)s2 * 16 + f];
        float4 d = X4[(size_t)s3 * 16 + f];
        acc.x += w0 * a.x + w1 * b.x + w2 * c.x + w3 * d.x;
        acc.y += w0 * a.y + w1 * b.y + w2 * c.y + w3 * d.y;
        acc.z += w0 * a.z + w1 * b.z + w2 * c.z + w3 * d.z;
        acc.w += w0 * a.w + w1 * b.w + w2 * c.w + w3 * d.w;
    }
    for (; j < deg; j++) {
        int s0 = csr[base + j];
        s0 = ((unsigned)s0 < (unsigned)N) ? s0 : 0;
        float w0 = dinv[s0];
        float4 a = X4[(size_t)s0 * 16 + f];
        acc.x += w0 * a.x;
        acc.y += w0 * a.y;
        acc.z += w0 * a.z;
        acc.w += w0 * a.w;
    }
    aggX4[(size_t)n * 16 + f] = acc;
}

// ---------------- MLP: t = dn*aggX[n]; h = elu(t@[Wn|Ws]+b); Zs[n] = half(dn * h@Wf) ----------------
// wave-per-node (grid-stride); lane l = dim l. Zs aliases aggX rows (stride 256B), fp16, 128B used.
__global__ __launch_bounds__(512) void k_mlp(
        const float* __restrict__ aggX, const float* __restrict__ dinv,
        const float* __restrict__ Wn, const float* __restrict__ bn,
        const float* __restrict__ Ws, const float* __restrict__ bs,
        const float* __restrict__ Wf, int N, __half* __restrict__ Zs) {
    __shared__ float sWn[32 * 128];      // sWn[i*128 + j] = Wn[i][j]
    __shared__ float sWs[32 * 128];
    __shared__ __half2 sWf2[128 * 64];   // sWf2[m2*64 + l] = (Wf[2m2][l], Wf[2m2+1][l])
    for (int idx = threadIdx.x; idx < 32 * 128; idx += blockDim.x) {
        sWn[idx] = Wn[idx];
        sWs[idx] = Ws[idx];
    }
    for (int idx = threadIdx.x; idx < 128 * 64; idx += blockDim.x) {
        int m2 = idx >> 6, l = idx & 63;
        sWf2[idx] = __floats2half2_rn(Wf[(2 * m2) * 64 + l], Wf[(2 * m2 + 1) * 64 + l]);
    }
    __syncthreads();

    int l = threadIdx.x & 63;
    int wpb = blockDim.x >> 6;
    int gw = blockIdx.x * wpb + (threadIdx.x >> 6);
    int nw = gridDim.x * wpb;
    float bn0 = bn[l], bn1 = bn[64 + l];
    float bs0 = bs[l], bs1 = bs[64 + l];

    for (int n = gw; n < N; n += nw) {
        float dn = dinv[n];
        float t = dn * aggX[(size_t)n * 64 + l];
        float h0 = bn0, h1 = bn1, h2 = bs0, h3 = bs1;
#pragma unroll
        for (int i = 0; i < 32; i++) {
            float a = __shfl(t, i);
            float cc = __shfl(t, 32 + i);
            h0 = fmaf(a, sWn[i * 128 + l], h0);
            h1 = fmaf(a, sWn[i * 128 + 64 + l], h1);
            h2 = fmaf(cc, sWs[i * 128 + l], h2);
            h3 = fmaf(cc, sWs[i * 128 + 64 + l], h3);
        }
        h0 = h0 > 0.f ? h0 : expm1f(h0);
        h1 = h1 > 0.f ? h1 : expm1f(h1);
        h2 = h2 > 0.f ? h2 : expm1f(h2);
        h3 = h3 > 0.f ? h3 : expm1f(h3);
        // y[l] = sum_m h_fused[m] * Wf[m][l]; fused rows: [0..63]=h0, [64..127]=h1, [128..191]=h2, [192..255]=h3
        float y = 0.f;
#pragma unroll 8
        for (int j2 = 0; j2 < 32; j2++) {
            __half2 u0 = sWf2[(j2) * 64 + l];
            __half2 u1 = sWf2[(32 + j2) * 64 + l];
            __half2 u2 = sWf2[(64 + j2) * 64 + l];
            __half2 u3 = sWf2[(96 + j2) * 64 + l];
            y = fmaf(__shfl(h0, 2 * j2), __low2float(u0), y);
            y = fmaf(__shfl(h0, 2 * j2 + 1), __high2float(u0), y);
            y = fmaf(__shfl(h1, 2 * j2), __low2float(u1), y);
            y = fmaf(__shfl(h1, 2 * j2 + 1), __high2float(u1), y);
            y = fmaf(__shfl(h2, 2 * j2), __low2float(u2), y);
            y = fmaf(__shfl(h2, 2 * j2 + 1), __high2float(u2), y);
            y = fmaf(__shfl(h3, 2 * j2), __low2float(u3), y);
            y = fmaf(__shfl(h3, 2 * j2 + 1), __high2float(u3), y);
        }
        Zs[(size_t)n * 128 + l] = __float2half_rn(dn * y);  // pre-scaled by dinv[n]
    }
}

// ---------------- layer-2 aggregation + bias + softmax ----------------
// thread = (node, 4-dim chunk); 16 threads per node; Zs rows are 64 halfs at stride 128 halfs (256B).
__global__ __launch_bounds__(256) void k_agg2(
        const uint2* __restrict__ Zu,  // 8B units; row stride 32 units
        const float* __restrict__ dinv,
        const int* __restrict__ offs, const int* __restrict__ cnt,
        const int* __restrict__ csr, const float4* __restrict__ bias4,
        int N, float4* __restrict__ out4) {
    int tid = blockIdx.x * blockDim.x + threadIdx.x;
    int n = tid >> 4;
    int f = tid & 15;
    if (n >= N) return;
    float ax = 0.f, ay = 0.f, az = 0.f, aw = 0.f;
    {
        uint2 p = Zu[(size_t)n * 32 + f];  // self (Zs already scaled by dinv[n])
        __half2 lo = *(__half2*)&p.x, hi = *(__half2*)&p.y;
        ax = __low2float(lo); ay = __high2float(lo);
        az = __low2float(hi); aw = __high2float(hi);
    }
    int base = offs[n], deg = cnt[n];
    int j = 0;
    for (; j + 4 <= deg; j += 4) {
        int s0 = csr[base + j];
        int s1 = csr[base + j + 1];
        int s2 = csr[base + j + 2];
        int s3 = csr[base + j + 3];
        s0 = ((unsigned)s0 < (unsigned)N) ? s0 : 0;
        s1 = ((unsigned)s1 < (unsigned)N) ? s1 : 0;
        s2 = ((unsigned)s2 < (unsigned)N) ? s2 : 0;
        s3 = ((unsigned)s3 < (unsigned)N) ? s3 : 0;
        uint2 p0 = Zu[(size_t)s0 * 32 + f];
        uint2 p1 = Zu[(size_t)s1 * 32 + f];
        uint2 p2 = Zu[(size_t)s2 * 32 + f];
        uint2 p3 = Zu[(size_t)s3 * 32 + f];
#pragma unroll
        for (int k = 0; k < 4; k++) {
            uint2 p = (k == 0) ? p0 : (k == 1) ? p1 : (k == 2) ? p2 : p3;
            __half2 lo = *(__half2*)&p.x, hi = *(__half2*)&p.y;
            ax += __low2float(lo); ay += __high2float(lo);
            az += __low2float(hi); aw += __high2float(hi);
        }
    }
    for (; j < deg; j++) {
        int s0 = csr[base + j];
        s0 = ((unsigned)s0 < (unsigned)N) ? s0 : 0;
        uint2 p = Zu[(size_t)s0 * 32 + f];
        __half2 lo = *(__half2*)&p.x, hi = *(__half2*)&p.y;
        ax += __low2float(lo); ay += __high2float(lo);
        az += __low2float(hi); aw += __high2float(hi);
    }
    float dn = dinv[n];
    float4 b = bias4[f];
    ax = dn * ax + b.x; ay = dn * ay + b.y; az = dn * az + b.z; aw = dn * aw + b.w;
    // softmax across the node's 64 dims = 16 lanes x 4
    float mx = fmaxf(fmaxf(ax, ay), fmaxf(az, aw));
    for (int o = 8; o >= 1; o >>= 1) mx = fmaxf(mx, __shfl_xor(mx, o));  // within 16-lane group
    float ex = expf(ax - mx), ey = expf(ay - mx), ez = expf(az - mx), ew = expf(aw - mx);
    float sm = ex + ey + ez + ew;
    for (int o = 8; o >= 1; o >>= 1) sm += __shfl_xor(sm, o);
    float inv = 1.f / sm;
    out4[(size_t)n * 16 + f] = make_float4(ex * inv, ey * inv, ez * inv, ew * inv);
}

extern "C" void kernel_launch(void* const* d_in, const int* in_sizes, int n_in,
                              void* d_out, int out_size, void* d_ws, size_t ws_size,
                              hipStream_t stream) {
    const float* X = (const float*)d_in[0];
    const int* ei = (const int*)d_in[1];
    // d_in[2] = batch (unused)
    const float* Wn = (const float*)d_in[3];
    const float* bn = (const float*)d_in[4];
    const float* Ws = (const float*)d_in[5];
    const float* bs = (const float*)d_in[6];
    const float* Wf = (const float*)d_in[7];
    const float* bfu = (const float*)d_in[8];

    const int N = in_sizes[2];        // 100000
    const int E = in_sizes[1] / 2;    // 1600000
    const int* src = ei;
    const int* dst = ei + E;

    // workspace layout (128-aligned); total ~33.6 MB
    char* ws = (char*)d_ws;
    int* cnt      = (int*)(ws + 0);            // 400000 B (pad -> 400128)
    int* cursor   = (int*)(ws + 400128);       // 400000 B (pad -> 800256)
    float* dinv   = (float*)(ws + 800256);     // 400000 B (pad -> 1200384)
    int* offs     = (int*)(ws + 1200384);      // 400000 B (pad -> 1600512)
    int* bsums    = (int*)(ws + 1600512);      // 256 B
    int* csr      = (int*)(ws + 1600768);      // 6400000 B -> 8000768
    float* aggX   = (float*)(ws + 8000768);    // 25600000 B -> 33600768 total
    __half* Zs    = (__half*)(ws + 8000768);   // aliases aggX: row n = halfs [n*128, n*128+64)

    hipMemsetAsync(ws, 0, 800256, stream);  // zero cnt + cursor

    int ebl = (E + 255) / 256;
    int nbl = (N + 255) / 256;
    int nb1 = (N + 2047) / 2048;  // 49 <= 64

    k_deg<<<ebl, 256, 0, stream>>>(dst, E, N, cnt);
    k_dinv<<<nbl, 256, 0, stream>>>(cnt, N, dinv);
    k_scan1<<<nb1, 256, 0, stream>>>(cnt, N, offs, bsums);
    k_scan2<<<1, 64, 0, stream>>>(bsums, nb1);
    k_scan3<<<nbl, 256, 0, stream>>>(offs, N, bsums);
    k_scatter<<<ebl, 256, 0, stream>>>(src, dst, E, N, offs, cursor, csr);

    int gbl = (N * 16 + 255) / 256;  // thread-per-(node, chunk)
    k_agg1<<<gbl, 256, 0, stream>>>((const float4*)X, dinv, offs, cnt, csr, N, (float4*)aggX);
    k_mlp<<<512, 512, 0, stream>>>(aggX, dinv, Wn, bn, Ws, bs, Wf, N, Zs);
    k_agg2<<<gbl, 256, 0, stream>>>((const uint2*)Zs, dinv, offs, cnt, csr,
                                    (const float4*)bfu, N, (float4*)d_out);
}

// Round 5
// 393.571 us; speedup vs baseline: 2.8062x; 2.2111x over previous
//
#include <hip/hip_runtime.h>
#include <hip/hip_fp16.h>

using half8 = __attribute__((ext_vector_type(8))) _Float16;
using f32x4 = __attribute__((ext_vector_type(4))) float;

// ---------------- degree / dinv ----------------
__global__ void k_deg(const int* __restrict__ dst, int E, int N, int* __restrict__ cnt) {
    int e = blockIdx.x * blockDim.x + threadIdx.x;
    if (e < E) {
        int d = dst[e];
        if ((unsigned)d < (unsigned)N) atomicAdd(&cnt[d], 1);
    }
}

__global__ void k_dinv(const int* __restrict__ cnt, int N, float* __restrict__ dinv) {
    int n = blockIdx.x * blockDim.x + threadIdx.x;
    if (n < N) dinv[n] = rsqrtf((float)(cnt[n] + 1));  // +1 self-loop; deg>=1 always
}

// ---------------- exclusive scan of cnt -> offs (2048 items/block) ----------------
__global__ void k_scan1(const int* __restrict__ cnt, int N,
                        int* __restrict__ offs, int* __restrict__ bsums) {
    __shared__ int sd[256];
    int t = threadIdx.x;
    int base = blockIdx.x * 2048 + t * 8;
    int v[8];
    int s = 0;
#pragma unroll
    for (int j = 0; j < 8; j++) {
        int i = base + j;
        v[j] = (i < N) ? cnt[i] : 0;
        s += v[j];
    }
    sd[t] = s;
    __syncthreads();
    for (int off = 1; off < 256; off <<= 1) {
        int x = (t >= off) ? sd[t - off] : 0;
        __syncthreads();
        sd[t] += x;
        __syncthreads();
    }
    int excl = (t == 0) ? 0 : sd[t - 1];
    if (t == 255) bsums[blockIdx.x] = sd[255];
    int run = excl;
#pragma unroll
    for (int j = 0; j < 8; j++) {
        int i = base + j;
        if (i < N) offs[i] = run;
        run += v[j];
    }
}

__global__ void k_scan2(int* __restrict__ bsums, int nb) {  // nb <= 64, one wave
    int t = threadIdx.x;
    int v = (t < nb) ? bsums[t] : 0;
    int orig = v;
    for (int off = 1; off < 64; off <<= 1) {
        int y = __shfl_up(v, off);
        if (t >= off) v += y;
    }
    if (t < nb) bsums[t] = v - orig;  // exclusive
}

__global__ void k_scan3(int* __restrict__ offs, int N, const int* __restrict__ bsums) {
    int i = blockIdx.x * blockDim.x + threadIdx.x;
    if (i < N) offs[i] += bsums[i >> 11];
}

// ---------------- CSR scatter (by dst, storing src) ----------------
__global__ void k_scatter(const int* __restrict__ src, const int* __restrict__ dst, int E, int N,
                          const int* __restrict__ offs, int* __restrict__ cursor,
                          int* __restrict__ csr) {
    int e = blockIdx.x * blockDim.x + threadIdx.x;
    if (e < E) {
        int d = dst[e];
        if ((unsigned)d < (unsigned)N) {
            int p = atomicAdd(&cursor[d], 1);
            csr[offs[d] + p] = src[e];
        }
    }
}

// ---------------- layer-1 aggregation: aggX[n] = dinv[n]*X[n] + sum_s dinv[s]*X[s] ----------------
__global__ __launch_bounds__(256) void k_agg1(
        const float4* __restrict__ X4, const float* __restrict__ dinv,
        const int* __restrict__ offs, const int* __restrict__ cnt,
        const int* __restrict__ csr, int N, float4* __restrict__ aggX4) {
    int tid = blockIdx.x * blockDim.x + threadIdx.x;
    int n = tid >> 4;
    int f = tid & 15;
    if (n >= N) return;
    float4 x = X4[(size_t)n * 16 + f];
    float w = dinv[n];
    float4 acc = make_float4(w * x.x, w * x.y, w * x.z, w * x.w);
    int base = offs[n], deg = cnt[n];
    int j = 0;
    for (; j + 4 <= deg; j += 4) {
        int s0 = csr[base + j];
        int s1 = csr[base + j + 1];
        int s2 = csr[base + j + 2];
        int s3 = csr[base + j + 3];
        s0 = ((unsigned)s0 < (unsigned)N) ? s0 : 0;
        s1 = ((unsigned)s1 < (unsigned)N) ? s1 : 0;
        s2 = ((unsigned)s2 < (unsigned)N) ? s2 : 0;
        s3 = ((unsigned)s3 < (unsigned)N) ? s3 : 0;
        float w0 = dinv[s0], w1 = dinv[s1], w2 = dinv[s2], w3 = dinv[s3];
        float4 a = X4[(size_t)s0 * 16 + f];
        float4 b = X4[(size_t)s1 * 16 + f];
        float4 c = X4[(size_t)s2 * 16 + f];
        float4 d = X4[(size_t)s3 * 16 + f];
        acc.x += w0 * a.x + w1 * b.x + w2 * c.x + w3 * d.x;
        acc.y += w0 * a.y + w1 * b.y + w2 * c.y + w3 * d.y;
        acc.z += w0 * a.z + w1 * b.z + w2 * c.z + w3 * d.z;
        acc.w += w0 * a.w + w1 * b.w + w2 * c.w + w3 * d.w;
    }
    for (; j < deg; j++) {
        int s0 = csr[base + j];
        s0 = ((unsigned)s0 < (unsigned)N) ? s0 : 0;
        float w0 = dinv[s0];
        float4 a = X4[(size_t)s0 * 16 + f];
        acc.x += w0 * a.x;
        acc.y += w0 * a.y;
        acc.z += w0 * a.z;
        acc.w += w0 * a.w;
    }
    aggX4[(size_t)n * 16 + f] = acc;
}

// ---------------- MFMA MLP: t = dn*aggX; h = elu(t@[Wn|Ws]+b); Zs = half(dn * h@Wf) ----------------
// wave-tile = 16 nodes. 16x16x32 f16 MFMA. A[m=lane&15][k=quad*8+j]; B[k=quad*8+j][n=lane&15];
// C/D col=lane&15, row=quad*4+reg (m89/m120-verified layouts).
// Layer-1 weight frags in VGPRs; Wf frags in LDS (32KB); per-wave H buffer (stride 272B: 2-way free).
__global__ __launch_bounds__(256) void k_mlp(
        const float* __restrict__ aggX, const float* __restrict__ dinv,
        const float* __restrict__ Wn, const float* __restrict__ bn,
        const float* __restrict__ Ws, const float* __restrict__ bs,
        const float* __restrict__ Wf, int N, __half* __restrict__ Zs) {
    __shared__ half8 sB2[32 * 64];           // Wf frags: tile (kt 0..7, nt 0..3) -> [tile*64 + lane]
    __shared__ _Float16 Hbuf[4][16 * 136];   // per-wave, one branch (16 nodes x 128 dims), stride 136 halfs

    const int l = threadIdx.x & 63;
    const int wid = threadIdx.x >> 6;
    const int q = l >> 4;
    const int n16 = l & 15;

    // prepack Wf fragments
    for (int e = threadIdx.x; e < 32 * 64; e += 256) {
        int tile = e >> 6, le = e & 63;
        int kt = tile >> 2, nt = tile & 3;
        int qq = le >> 4, nn = le & 15;
        half8 v;
#pragma unroll
        for (int j = 0; j < 8; j++)
            v[j] = (_Float16)Wf[(kt * 32 + qq * 8 + j) * 64 + nt * 16 + nn];
        sB2[e] = v;
    }
    __syncthreads();

    // layer-1 weight fragments in registers (K=32 per branch -> one k-tile)
    half8 w1n[8], w1s[8];
#pragma unroll
    for (int nt = 0; nt < 8; nt++) {
        half8 a, b;
#pragma unroll
        for (int j = 0; j < 8; j++) {
            a[j] = (_Float16)Wn[(q * 8 + j) * 128 + nt * 16 + n16];
            b[j] = (_Float16)Ws[(q * 8 + j) * 128 + nt * 16 + n16];
        }
        w1n[nt] = a;
        w1s[nt] = b;
    }
    float bnr[8], bsr[8];
#pragma unroll
    for (int nt = 0; nt < 8; nt++) {
        bnr[nt] = bn[nt * 16 + n16];
        bsr[nt] = bs[nt * 16 + n16];
    }

    const int ntiles = (N + 15) >> 4;
    const int nw = gridDim.x * 4;
    const float4* A4 = (const float4*)aggX;
    _Float16* Hw = Hbuf[wid];

    for (int tile = blockIdx.x * 4 + wid; tile < ntiles; tile += nw) {
        int nb = tile << 4;
        int nodeA = nb + n16;
        if (nodeA >= N) nodeA = N - 1;
        float dn = dinv[nodeA];
        // A fragments for both branches (branch n = dims 0..31, branch s = 32..63)
        float4 f0 = A4[(size_t)nodeA * 16 + q * 2];
        float4 f1 = A4[(size_t)nodeA * 16 + q * 2 + 1];
        float4 g0 = A4[(size_t)nodeA * 16 + 8 + q * 2];
        float4 g1 = A4[(size_t)nodeA * 16 + 8 + q * 2 + 1];
        half8 an, as;
        an[0] = (_Float16)(dn * f0.x); an[1] = (_Float16)(dn * f0.y);
        an[2] = (_Float16)(dn * f0.z); an[3] = (_Float16)(dn * f0.w);
        an[4] = (_Float16)(dn * f1.x); an[5] = (_Float16)(dn * f1.y);
        an[6] = (_Float16)(dn * f1.z); an[7] = (_Float16)(dn * f1.w);
        as[0] = (_Float16)(dn * g0.x); as[1] = (_Float16)(dn * g0.y);
        as[2] = (_Float16)(dn * g0.z); as[3] = (_Float16)(dn * g0.w);
        as[4] = (_Float16)(dn * g1.x); as[5] = (_Float16)(dn * g1.y);
        as[6] = (_Float16)(dn * g1.z); as[7] = (_Float16)(dn * g1.w);

        f32x4 Y[4];
#pragma unroll
        for (int i = 0; i < 4; i++) Y[i] = (f32x4){0.f, 0.f, 0.f, 0.f};

        // ===== branch n =====
        f32x4 c1[8];
#pragma unroll
        for (int nt = 0; nt < 8; nt++)
            c1[nt] = __builtin_amdgcn_mfma_f32_16x16x32_f16(an, w1n[nt], (f32x4){0.f, 0.f, 0.f, 0.f}, 0, 0, 0);
#pragma unroll
        for (int nt = 0; nt < 8; nt++) {
#pragma unroll
            for (int r = 0; r < 4; r++) {
                float v = c1[nt][r] + bnr[nt];
                v = v > 0.f ? v : expm1f(v);
                Hw[(q * 4 + r) * 136 + nt * 16 + n16] = (_Float16)v;  // H[node_row][h_dim]
            }
        }
#pragma unroll
        for (int kt = 0; kt < 4; kt++) {
            half8 ha = *(const half8*)&Hw[n16 * 136 + kt * 32 + q * 8];  // A-layout read
#pragma unroll
            for (int nt2 = 0; nt2 < 4; nt2++)
                Y[nt2] = __builtin_amdgcn_mfma_f32_16x16x32_f16(ha, sB2[(kt * 4 + nt2) * 64 + l], Y[nt2], 0, 0, 0);
        }
        // ===== branch s ===== (in-wave DS ops are in-order: WAR on Hbuf is safe)
#pragma unroll
        for (int nt = 0; nt < 8; nt++)
            c1[nt] = __builtin_amdgcn_mfma_f32_16x16x32_f16(as, w1s[nt], (f32x4){0.f, 0.f, 0.f, 0.f}, 0, 0, 0);
#pragma unroll
        for (int nt = 0; nt < 8; nt++) {
#pragma unroll
            for (int r = 0; r < 4; r++) {
                float v = c1[nt][r] + bsr[nt];
                v = v > 0.f ? v : expm1f(v);
                Hw[(q * 4 + r) * 136 + nt * 16 + n16] = (_Float16)v;
            }
        }
#pragma unroll
        for (int kt = 0; kt < 4; kt++) {
            half8 ha = *(const half8*)&Hw[n16 * 136 + kt * 32 + q * 8];
#pragma unroll
            for (int nt2 = 0; nt2 < 4; nt2++)
                Y[nt2] = __builtin_amdgcn_mfma_f32_16x16x32_f16(ha, sB2[((4 + kt) * 4 + nt2) * 64 + l], Y[nt2], 0, 0, 0);
        }
        // ===== epilogue: Zs[node][dim] = half(dinv[node] * Y) =====
        float dnr[4];
#pragma unroll
        for (int r = 0; r < 4; r++) dnr[r] = __shfl(dn, q * 4 + r);  // lanes 0..15 hold dinv[nb+0..15]
#pragma unroll
        for (int r = 0; r < 4; r++) {
            int node = nb + q * 4 + r;
            if (node < N) {
#pragma unroll
                for (int nt2 = 0; nt2 < 4; nt2++)
                    Zs[(size_t)node * 128 + nt2 * 16 + n16] = __float2half_rn(dnr[r] * Y[nt2][r]);
            }
        }
    }
}

// ---------------- layer-2 aggregation + bias + softmax ----------------
__global__ __launch_bounds__(256) void k_agg2(
        const uint2* __restrict__ Zu,  // 8B units; row stride 32 units
        const float* __restrict__ dinv,
        const int* __restrict__ offs, const int* __restrict__ cnt,
        const int* __restrict__ csr, const float4* __restrict__ bias4,
        int N, float4* __restrict__ out4) {
    int tid = blockIdx.x * blockDim.x + threadIdx.x;
    int n = tid >> 4;
    int f = tid & 15;
    if (n >= N) return;
    float ax = 0.f, ay = 0.f, az = 0.f, aw = 0.f;
    {
        uint2 p = Zu[(size_t)n * 32 + f];  // self (Zs already scaled by dinv[n])
        __half2 lo = *(__half2*)&p.x, hi = *(__half2*)&p.y;
        ax = __low2float(lo); ay = __high2float(lo);
        az = __low2float(hi); aw = __high2float(hi);
    }
    int base = offs[n], deg = cnt[n];
    int j = 0;
    for (; j + 4 <= deg; j += 4) {
        int s0 = csr[base + j];
        int s1 = csr[base + j + 1];
        int s2 = csr[base + j + 2];
        int s3 = csr[base + j + 3];
        s0 = ((unsigned)s0 < (unsigned)N) ? s0 : 0;
        s1 = ((unsigned)s1 < (unsigned)N) ? s1 : 0;
        s2 = ((unsigned)s2 < (unsigned)N) ? s2 : 0;
        s3 = ((unsigned)s3 < (unsigned)N) ? s3 : 0;
        uint2 p0 = Zu[(size_t)s0 * 32 + f];
        uint2 p1 = Zu[(size_t)s1 * 32 + f];
        uint2 p2 = Zu[(size_t)s2 * 32 + f];
        uint2 p3 = Zu[(size_t)s3 * 32 + f];
#pragma unroll
        for (int k = 0; k < 4; k++) {
            uint2 p = (k == 0) ? p0 : (k == 1) ? p1 : (k == 2) ? p2 : p3;
            __half2 lo = *(__half2*)&p.x, hi = *(__half2*)&p.y;
            ax += __low2float(lo); ay += __high2float(lo);
            az += __low2float(hi); aw += __high2float(hi);
        }
    }
    for (; j < deg; j++) {
        int s0 = csr[base + j];
        s0 = ((unsigned)s0 < (unsigned)N) ? s0 : 0;
        uint2 p = Zu[(size_t)s0 * 32 + f];
        __half2 lo = *(__half2*)&p.x, hi = *(__half2*)&p.y;
        ax += __low2float(lo); ay += __high2float(lo);
        az += __low2float(hi); aw += __high2float(hi);
    }
    float dn = dinv[n];
    float4 b = bias4[f];
    ax = dn * ax + b.x; ay = dn * ay + b.y; az = dn * az + b.z; aw = dn * aw + b.w;
    // softmax across the node's 64 dims = 16 lanes x 4
    float mx = fmaxf(fmaxf(ax, ay), fmaxf(az, aw));
    for (int o = 8; o >= 1; o >>= 1) mx = fmaxf(mx, __shfl_xor(mx, o));
    float ex = expf(ax - mx), ey = expf(ay - mx), ez = expf(az - mx), ew = expf(aw - mx);
    float sm = ex + ey + ez + ew;
    for (int o = 8; o >= 1; o >>= 1) sm += __shfl_xor(sm, o);
    float inv = 1.f / sm;
    out4[(size_t)n * 16 + f] = make_float4(ex * inv, ey * inv, ez * inv, ew * inv);
}

extern "C" void kernel_launch(void* const* d_in, const int* in_sizes, int n_in,
                              void* d_out, int out_size, void* d_ws, size_t ws_size,
                              hipStream_t stream) {
    const float* X = (const float*)d_in[0];
    const int* ei = (const int*)d_in[1];
    // d_in[2] = batch (unused)
    const float* Wn = (const float*)d_in[3];
    const float* bn = (const float*)d_in[4];
    const float* Ws = (const float*)d_in[5];
    const float* bs = (const float*)d_in[6];
    const float* Wf = (const float*)d_in[7];
    const float* bfu = (const float*)d_in[8];

    const int N = in_sizes[2];        // 100000
    const int E = in_sizes[1] / 2;    // 1600000
    const int* src = ei;
    const int* dst = ei + E;

    // workspace layout (128-aligned); total ~33.6 MB
    char* ws = (char*)d_ws;
    int* cnt      = (int*)(ws + 0);            // 400000 B (pad -> 400128)
    int* cursor   = (int*)(ws + 400128);       // 400000 B (pad -> 800256)
    float* dinv   = (float*)(ws + 800256);     // 400000 B (pad -> 1200384)
    int* offs     = (int*)(ws + 1200384);      // 400000 B (pad -> 1600512)
    int* bsums    = (int*)(ws + 1600512);      // 256 B
    int* csr      = (int*)(ws + 1600768);      // 6400000 B -> 8000768
    float* aggX   = (float*)(ws + 8000768);    // 25600000 B -> 33600768 total
    __half* Zs    = (__half*)(ws + 8000768);   // aliases aggX: row n = halfs [n*128, n*128+64)

    hipMemsetAsync(ws, 0, 800256, stream);  // zero cnt + cursor

    int ebl = (E + 255) / 256;
    int nbl = (N + 255) / 256;
    int nb1 = (N + 2047) / 2048;  // 49 <= 64

    k_deg<<<ebl, 256, 0, stream>>>(dst, E, N, cnt);
    k_dinv<<<nbl, 256, 0, stream>>>(cnt, N, dinv);
    k_scan1<<<nb1, 256, 0, stream>>>(cnt, N, offs, bsums);
    k_scan2<<<1, 64, 0, stream>>>(bsums, nb1);
    k_scan3<<<nbl, 256, 0, stream>>>(offs, N, bsums);
    k_scatter<<<ebl, 256, 0, stream>>>(src, dst, E, N, offs, cursor, csr);

    int gbl = (N * 16 + 255) / 256;  // thread-per-(node, chunk)
    k_agg1<<<gbl, 256, 0, stream>>>((const float4*)X, dinv, offs, cnt, csr, N, (float4*)aggX);
    k_mlp<<<512, 256, 0, stream>>>(aggX, dinv, Wn, bn, Ws, bs, Wf, N, Zs);
    k_agg2<<<gbl, 256, 0, stream>>>((const uint2*)Zs, dinv, offs, cnt, csr,
                                    (const float4*)bfu, N, (float4*)d_out);
}

// Round 6
// 359.988 us; speedup vs baseline: 3.0680x; 1.0933x over previous
//
#include <hip/hip_runtime.h>
#include <hip/hip_fp16.h>

using half8 = __attribute__((ext_vector_type(8))) _Float16;
using f32x4 = __attribute__((ext_vector_type(4))) float;

// ============ bucketed CSR build ============
// bucket = min(dst >> 10, 127); 128 buckets cover N=100000 (98 used).

__global__ __launch_bounds__(256) void k_bhist(const int* __restrict__ dst, int E, int N,
                                               int* __restrict__ bcur) {
    __shared__ int h[128];
    for (int i = threadIdx.x; i < 128; i += 256) h[i] = 0;
    __syncthreads();
    for (int e = blockIdx.x * blockDim.x + threadIdx.x; e < E; e += gridDim.x * blockDim.x) {
        int d = dst[e];
        d = ((unsigned)d < (unsigned)N) ? d : 0;
        atomicAdd(&h[min(d >> 10, 127)], 1);
    }
    __syncthreads();
    for (int i = threadIdx.x; i < 128; i += 256) if (h[i]) atomicAdd(&bcur[i], h[i]);
}

__global__ void k_bscan(int* __restrict__ bcur) {  // 1 block x 128 threads, exclusive scan
    __shared__ int sd[128];
    int t = threadIdx.x;
    int v = bcur[t];
    sd[t] = v;
    __syncthreads();
    for (int off = 1; off < 128; off <<= 1) {
        int x = (t >= off) ? sd[t - off] : 0;
        __syncthreads();
        sd[t] += x;
        __syncthreads();
    }
    bcur[t] = (t == 0) ? 0 : sd[t - 1];
}

// partition edges into bucket-ordered ebuf (uint2{src,dst}); per-block contiguous runs per bucket
__global__ __launch_bounds__(256) void k_part(const int* __restrict__ src, const int* __restrict__ dst,
                                              int E, int N, int* __restrict__ bcur,
                                              uint2* __restrict__ ebuf) {
    __shared__ int lcnt[128], lbase[128];
    int t = threadIdx.x;
    int e0 = blockIdx.x * 4096;
    int s[16], d[16];
    for (int i = t; i < 128; i += 256) lcnt[i] = 0;
    __syncthreads();
#pragma unroll
    for (int j = 0; j < 16; j++) {
        int e = e0 + j * 256 + t;
        if (e < E) {
            int dd = dst[e];
            dd = ((unsigned)dd < (unsigned)N) ? dd : 0;  // clamp: consistent everywhere
            d[j] = dd;
            s[j] = src[e];
            atomicAdd(&lcnt[min(dd >> 10, 127)], 1);
        } else d[j] = -1;
    }
    __syncthreads();
    for (int i = t; i < 128; i += 256) lbase[i] = lcnt[i] ? atomicAdd(&bcur[i], lcnt[i]) : 0;
    __syncthreads();
    for (int i = t; i < 128; i += 256) lcnt[i] = 0;
    __syncthreads();
#pragma unroll
    for (int j = 0; j < 16; j++) {
        if (d[j] >= 0) {
            int bk = min(d[j] >> 10, 127);
            int pos = lbase[bk] + atomicAdd(&lcnt[bk], 1);
            ebuf[pos] = make_uint2((unsigned)s[j], (unsigned)d[j]);
        }
    }
}

// degree count over bucket-ordered edges (block-contiguous spans -> L2-local atomics)
__global__ __launch_bounds__(256) void k_deg2(const uint2* __restrict__ ebuf, int E,
                                              int* __restrict__ cnt) {
    int e0 = blockIdx.x * 4096;
#pragma unroll
    for (int j = 0; j < 16; j++) {
        int e = e0 + j * 256 + threadIdx.x;
        if (e < E) atomicAdd(&cnt[ebuf[e].y], 1);
    }
}

__global__ void k_dinv(const int* __restrict__ cnt, int N, float* __restrict__ dinv) {
    int n = blockIdx.x * blockDim.x + threadIdx.x;
    if (n < N) dinv[n] = rsqrtf((float)(cnt[n] + 1));  // +1 self-loop
}

// ---------------- exclusive scan of cnt -> offs (2048 items/block) ----------------
__global__ void k_scan1(const int* __restrict__ cnt, int N,
                        int* __restrict__ offs, int* __restrict__ bsums) {
    __shared__ int sd[256];
    int t = threadIdx.x;
    int base = blockIdx.x * 2048 + t * 8;
    int v[8];
    int s = 0;
#pragma unroll
    for (int j = 0; j < 8; j++) {
        int i = base + j;
        v[j] = (i < N) ? cnt[i] : 0;
        s += v[j];
    }
    sd[t] = s;
    __syncthreads();
    for (int off = 1; off < 256; off <<= 1) {
        int x = (t >= off) ? sd[t - off] : 0;
        __syncthreads();
        sd[t] += x;
        __syncthreads();
    }
    int excl = (t == 0) ? 0 : sd[t - 1];
    if (t == 255) bsums[blockIdx.x] = sd[255];
    int run = excl;
#pragma unroll
    for (int j = 0; j < 8; j++) {
        int i = base + j;
        if (i < N) offs[i] = run;
        run += v[j];
    }
}

__global__ void k_scan2(int* __restrict__ bsums, int nb) {  // nb <= 64, one wave
    int t = threadIdx.x;
    int v = (t < nb) ? bsums[t] : 0;
    int orig = v;
    for (int off = 1; off < 64; off <<= 1) {
        int y = __shfl_up(v, off);
        if (t >= off) v += y;
    }
    if (t < nb) bsums[t] = v - orig;  // exclusive
}

__global__ void k_scan3(int* __restrict__ offs, int N, const int* __restrict__ bsums) {
    int i = blockIdx.x * blockDim.x + threadIdx.x;
    if (i < N) offs[i] += bsums[i >> 11];
}

// final CSR scatter over bucket-ordered edges: writes confined to ~64KB window per block
__global__ __launch_bounds__(256) void k_scat2(const uint2* __restrict__ ebuf, int E,
                                               const int* __restrict__ offs, int* __restrict__ cursor,
                                               int* __restrict__ csr) {
    int e0 = blockIdx.x * 4096;
#pragma unroll
    for (int j = 0; j < 16; j++) {
        int e = e0 + j * 256 + threadIdx.x;
        if (e < E) {
            uint2 p = ebuf[e];
            int d = p.y;
            int pos = atomicAdd(&cursor[d], 1);
            csr[offs[d] + pos] = (int)p.x;
        }
    }
}

// ---------------- layer-1 aggregation: aggX[n] = dinv[n]*X[n] + sum_s dinv[s]*X[s] ----------------
__global__ __launch_bounds__(256) void k_agg1(
        const float4* __restrict__ X4, const float* __restrict__ dinv,
        const int* __restrict__ offs, const int* __restrict__ cnt,
        const int* __restrict__ csr, int N, float4* __restrict__ aggX4) {
    int tid = blockIdx.x * blockDim.x + threadIdx.x;
    int n = tid >> 4;
    int f = tid & 15;
    if (n >= N) return;
    float4 x = X4[(size_t)n * 16 + f];
    float w = dinv[n];
    float4 acc = make_float4(w * x.x, w * x.y, w * x.z, w * x.w);
    int base = offs[n], deg = cnt[n];
    int j = 0;
    for (; j + 4 <= deg; j += 4) {
        int s0 = csr[base + j];
        int s1 = csr[base + j + 1];
        int s2 = csr[base + j + 2];
        int s3 = csr[base + j + 3];
        s0 = ((unsigned)s0 < (unsigned)N) ? s0 : 0;
        s1 = ((unsigned)s1 < (unsigned)N) ? s1 : 0;
        s2 = ((unsigned)s2 < (unsigned)N) ? s2 : 0;
        s3 = ((unsigned)s3 < (unsigned)N) ? s3 : 0;
        float w0 = dinv[s0], w1 = dinv[s1], w2 = dinv[s2], w3 = dinv[s3];
        float4 a = X4[(size_t)s0 * 16 + f];
        float4 b = X4[(size_t)s1 * 16 + f];
        float4 c = X4[(size_t)s2 * 16 + f];
        float4 d = X4[(size_t)s3 * 16 + f];
        acc.x += w0 * a.x + w1 * b.x + w2 * c.x + w3 * d.x;
        acc.y += w0 * a.y + w1 * b.y + w2 * c.y + w3 * d.y;
        acc.z += w0 * a.z + w1 * b.z + w2 * c.z + w3 * d.z;
        acc.w += w0 * a.w + w1 * b.w + w2 * c.w + w3 * d.w;
    }
    for (; j < deg; j++) {
        int s0 = csr[base + j];
        s0 = ((unsigned)s0 < (unsigned)N) ? s0 : 0;
        float w0 = dinv[s0];
        float4 a = X4[(size_t)s0 * 16 + f];
        acc.x += w0 * a.x;
        acc.y += w0 * a.y;
        acc.z += w0 * a.z;
        acc.w += w0 * a.w;
    }
    aggX4[(size_t)n * 16 + f] = acc;
}

// ---------------- MFMA MLP (unchanged from R5) ----------------
__global__ __launch_bounds__(256) void k_mlp(
        const float* __restrict__ aggX, const float* __restrict__ dinv,
        const float* __restrict__ Wn, const float* __restrict__ bn,
        const float* __restrict__ Ws, const float* __restrict__ bs,
        const float* __restrict__ Wf, int N, __half* __restrict__ Zs) {
    __shared__ half8 sB2[32 * 64];
    __shared__ _Float16 Hbuf[4][16 * 136];

    const int l = threadIdx.x & 63;
    const int wid = threadIdx.x >> 6;
    const int q = l >> 4;
    const int n16 = l & 15;

    for (int e = threadIdx.x; e < 32 * 64; e += 256) {
        int tile = e >> 6, le = e & 63;
        int kt = tile >> 2, nt = tile & 3;
        int qq = le >> 4, nn = le & 15;
        half8 v;
#pragma unroll
        for (int j = 0; j < 8; j++)
            v[j] = (_Float16)Wf[(kt * 32 + qq * 8 + j) * 64 + nt * 16 + nn];
        sB2[e] = v;
    }
    __syncthreads();

    half8 w1n[8], w1s[8];
#pragma unroll
    for (int nt = 0; nt < 8; nt++) {
        half8 a, b;
#pragma unroll
        for (int j = 0; j < 8; j++) {
            a[j] = (_Float16)Wn[(q * 8 + j) * 128 + nt * 16 + n16];
            b[j] = (_Float16)Ws[(q * 8 + j) * 128 + nt * 16 + n16];
        }
        w1n[nt] = a;
        w1s[nt] = b;
    }
    float bnr[8], bsr[8];
#pragma unroll
    for (int nt = 0; nt < 8; nt++) {
        bnr[nt] = bn[nt * 16 + n16];
        bsr[nt] = bs[nt * 16 + n16];
    }

    const int ntiles = (N + 15) >> 4;
    const int nw = gridDim.x * 4;
    const float4* A4 = (const float4*)aggX;
    _Float16* Hw = Hbuf[wid];

    for (int tile = blockIdx.x * 4 + wid; tile < ntiles; tile += nw) {
        int nb = tile << 4;
        int nodeA = nb + n16;
        if (nodeA >= N) nodeA = N - 1;
        float dn = dinv[nodeA];
        float4 f0 = A4[(size_t)nodeA * 16 + q * 2];
        float4 f1 = A4[(size_t)nodeA * 16 + q * 2 + 1];
        float4 g0 = A4[(size_t)nodeA * 16 + 8 + q * 2];
        float4 g1 = A4[(size_t)nodeA * 16 + 8 + q * 2 + 1];
        half8 an, as;
        an[0] = (_Float16)(dn * f0.x); an[1] = (_Float16)(dn * f0.y);
        an[2] = (_Float16)(dn * f0.z); an[3] = (_Float16)(dn * f0.w);
        an[4] = (_Float16)(dn * f1.x); an[5] = (_Float16)(dn * f1.y);
        an[6] = (_Float16)(dn * f1.z); an[7] = (_Float16)(dn * f1.w);
        as[0] = (_Float16)(dn * g0.x); as[1] = (_Float16)(dn * g0.y);
        as[2] = (_Float16)(dn * g0.z); as[3] = (_Float16)(dn * g0.w);
        as[4] = (_Float16)(dn * g1.x); as[5] = (_Float16)(dn * g1.y);
        as[6] = (_Float16)(dn * g1.z); as[7] = (_Float16)(dn * g1.w);

        f32x4 Y[4];
#pragma unroll
        for (int i = 0; i < 4; i++) Y[i] = (f32x4){0.f, 0.f, 0.f, 0.f};

        f32x4 c1[8];
#pragma unroll
        for (int nt = 0; nt < 8; nt++)
            c1[nt] = __builtin_amdgcn_mfma_f32_16x16x32_f16(an, w1n[nt], (f32x4){0.f, 0.f, 0.f, 0.f}, 0, 0, 0);
#pragma unroll
        for (int nt = 0; nt < 8; nt++) {
#pragma unroll
            for (int r = 0; r < 4; r++) {
                float v = c1[nt][r] + bnr[nt];
                v = v > 0.f ? v : expm1f(v);
                Hw[(q * 4 + r) * 136 + nt * 16 + n16] = (_Float16)v;
            }
        }
#pragma unroll
        for (int kt = 0; kt < 4; kt++) {
            half8 ha = *(const half8*)&Hw[n16 * 136 + kt * 32 + q * 8];
#pragma unroll
            for (int nt2 = 0; nt2 < 4; nt2++)
                Y[nt2] = __builtin_amdgcn_mfma_f32_16x16x32_f16(ha, sB2[(kt * 4 + nt2) * 64 + l], Y[nt2], 0, 0, 0);
        }
#pragma unroll
        for (int nt = 0; nt < 8; nt++)
            c1[nt] = __builtin_amdgcn_mfma_f32_16x16x32_f16(as, w1s[nt], (f32x4){0.f, 0.f, 0.f, 0.f}, 0, 0, 0);
#pragma unroll
        for (int nt = 0; nt < 8; nt++) {
#pragma unroll
            for (int r = 0; r < 4; r++) {
                float v = c1[nt][r] + bsr[nt];
                v = v > 0.f ? v : expm1f(v);
                Hw[(q * 4 + r) * 136 + nt * 16 + n16] = (_Float16)v;
            }
        }
#pragma unroll
        for (int kt = 0; kt < 4; kt++) {
            half8 ha = *(const half8*)&Hw[n16 * 136 + kt * 32 + q * 8];
#pragma unroll
            for (int nt2 = 0; nt2 < 4; nt2++)
                Y[nt2] = __builtin_amdgcn_mfma_f32_16x16x32_f16(ha, sB2[((4 + kt) * 4 + nt2) * 64 + l], Y[nt2], 0, 0, 0);
        }
        float dnr[4];
#pragma unroll
        for (int r = 0; r < 4; r++) dnr[r] = __shfl(dn, q * 4 + r);
#pragma unroll
        for (int r = 0; r < 4; r++) {
            int node = nb + q * 4 + r;
            if (node < N) {
#pragma unroll
                for (int nt2 = 0; nt2 < 4; nt2++)
                    Zs[(size_t)node * 128 + nt2 * 16 + n16] = __float2half_rn(dnr[r] * Y[nt2][r]);
            }
        }
    }
}

// ---------------- layer-2 aggregation + bias + softmax ----------------
__global__ __launch_bounds__(256) void k_agg2(
        const uint2* __restrict__ Zu, const float* __restrict__ dinv,
        const int* __restrict__ offs, const int* __restrict__ cnt,
        const int* __restrict__ csr, const float4* __restrict__ bias4,
        int N, float4* __restrict__ out4) {
    int tid = blockIdx.x * blockDim.x + threadIdx.x;
    int n = tid >> 4;
    int f = tid & 15;
    if (n >= N) return;
    float ax = 0.f, ay = 0.f, az = 0.f, aw = 0.f;
    {
        uint2 p = Zu[(size_t)n * 32 + f];
        __half2 lo = *(__half2*)&p.x, hi = *(__half2*)&p.y;
        ax = __low2float(lo); ay = __high2float(lo);
        az = __low2float(hi); aw = __high2float(hi);
    }
    int base = offs[n], deg = cnt[n];
    int j = 0;
    for (; j + 4 <= deg; j += 4) {
        int s0 = csr[base + j];
        int s1 = csr[base + j + 1];
        int s2 = csr[base + j + 2];
        int s3 = csr[base + j + 3];
        s0 = ((unsigned)s0 < (unsigned)N) ? s0 : 0;
        s1 = ((unsigned)s1 < (unsigned)N) ? s1 : 0;
        s2 = ((unsigned)s2 < (unsigned)N) ? s2 : 0;
        s3 = ((unsigned)s3 < (unsigned)N) ? s3 : 0;
        uint2 p0 = Zu[(size_t)s0 * 32 + f];
        uint2 p1 = Zu[(size_t)s1 * 32 + f];
        uint2 p2 = Zu[(size_t)s2 * 32 + f];
        uint2 p3 = Zu[(size_t)s3 * 32 + f];
#pragma unroll
        for (int k = 0; k < 4; k++) {
            uint2 p = (k == 0) ? p0 : (k == 1) ? p1 : (k == 2) ? p2 : p3;
            __half2 lo = *(__half2*)&p.x, hi = *(__half2*)&p.y;
            ax += __low2float(lo); ay += __high2float(lo);
            az += __low2float(hi); aw += __high2float(hi);
        }
    }
    for (; j < deg; j++) {
        int s0 = csr[base + j];
        s0 = ((unsigned)s0 < (unsigned)N) ? s0 : 0;
        uint2 p = Zu[(size_t)s0 * 32 + f];
        __half2 lo = *(__half2*)&p.x, hi = *(__half2*)&p.y;
        ax += __low2float(lo); ay += __high2float(lo);
        az += __low2float(hi); aw += __high2float(hi);
    }
    float dn = dinv[n];
    float4 b = bias4[f];
    ax = dn * ax + b.x; ay = dn * ay + b.y; az = dn * az + b.z; aw = dn * aw + b.w;
    float mx = fmaxf(fmaxf(ax, ay), fmaxf(az, aw));
    for (int o = 8; o >= 1; o >>= 1) mx = fmaxf(mx, __shfl_xor(mx, o));
    float ex = expf(ax - mx), ey = expf(ay - mx), ez = expf(az - mx), ew = expf(aw - mx);
    float sm = ex + ey + ez + ew;
    for (int o = 8; o >= 1; o >>= 1) sm += __shfl_xor(sm, o);
    float inv = 1.f / sm;
    out4[(size_t)n * 16 + f] = make_float4(ex * inv, ey * inv, ez * inv, ew * inv);
}

extern "C" void kernel_launch(void* const* d_in, const int* in_sizes, int n_in,
                              void* d_out, int out_size, void* d_ws, size_t ws_size,
                              hipStream_t stream) {
    const float* X = (const float*)d_in[0];
    const int* ei = (const int*)d_in[1];
    // d_in[2] = batch (unused)
    const float* Wn = (const float*)d_in[3];
    const float* bn = (const float*)d_in[4];
    const float* Ws = (const float*)d_in[5];
    const float* bs = (const float*)d_in[6];
    const float* Wf = (const float*)d_in[7];
    const float* bfu = (const float*)d_in[8];

    const int N = in_sizes[2];        // 100000
    const int E = in_sizes[1] / 2;    // 1600000
    const int* src = ei;
    const int* dst = ei + E;

    // workspace layout (128-aligned); total ~33.6 MB
    char* ws = (char*)d_ws;
    int* cnt      = (int*)(ws + 0);            // 400000 -> pad 400128
    int* cursor   = (int*)(ws + 400128);       // 400000 -> pad 800256
    int* bcur     = (int*)(ws + 800256);       // 512    -> 800768
    float* dinv   = (float*)(ws + 800768);     // 400000 -> 1200768
    int* offs     = (int*)(ws + 1200768);      // 400000 -> 1600768
    int* bsums    = (int*)(ws + 1600768);      // 256    -> 1601024
    int* csr      = (int*)(ws + 1601024);      // 6400000 -> 8001024
    float* aggX   = (float*)(ws + 8001024);    // 25600000 -> 33601024 total
    uint2* ebuf   = (uint2*)(ws + 8001024);    // 12800000, aliases aggX (dead before k_agg1)
    __half* Zs    = (__half*)(ws + 8001024);   // aliases aggX: row n = halfs [n*128, n*128+64)

    hipMemsetAsync(ws, 0, 800768, stream);  // zero cnt + cursor + bcur

    int nbl = (N + 255) / 256;
    int nb1 = (N + 2047) / 2048;     // 49 <= 64
    int pbl = (E + 4095) / 4096;     // 391 blocks, 4096 edges each

    k_bhist<<<pbl, 256, 0, stream>>>(dst, E, N, bcur);
    k_bscan<<<1, 128, 0, stream>>>(bcur);
    k_part<<<pbl, 256, 0, stream>>>(src, dst, E, N, bcur, ebuf);
    k_deg2<<<pbl, 256, 0, stream>>>(ebuf, E, cnt);
    k_dinv<<<nbl, 256, 0, stream>>>(cnt, N, dinv);
    k_scan1<<<nb1, 256, 0, stream>>>(cnt, N, offs, bsums);
    k_scan2<<<1, 64, 0, stream>>>(bsums, nb1);
    k_scan3<<<nbl, 256, 0, stream>>>(offs, N, bsums);
    k_scat2<<<pbl, 256, 0, stream>>>(ebuf, E, offs, cursor, csr);

    int gbl = (N * 16 + 255) / 256;  // thread-per-(node, chunk)
    k_agg1<<<gbl, 256, 0, stream>>>((const float4*)X, dinv, offs, cnt, csr, N, (float4*)aggX);
    k_mlp<<<512, 256, 0, stream>>>(aggX, dinv, Wn, bn, Ws, bs, Wf, N, Zs);
    k_agg2<<<gbl, 256, 0, stream>>>((const uint2*)Zs, dinv, offs, cnt, csr,
                                    (const float4*)bfu, N, (float4*)d_out);
}

// Round 7
// 348.663 us; speedup vs baseline: 3.1677x; 1.0325x over previous
//
#include <hip/hip_runtime.h>
#include <hip/hip_fp16.h>

using half8 = __attribute__((ext_vector_type(8))) _Float16;
using f32x4 = __attribute__((ext_vector_type(4))) float;

// ============ bucketed CSR build ============
// bucket = min(dst >> 10, 127); 128 buckets cover N=100000 (98 used).

__global__ __launch_bounds__(256) void k_bhist(const int* __restrict__ dst, int E, int N,
                                               int* __restrict__ bcur) {
    __shared__ int h[128];
    for (int i = threadIdx.x; i < 128; i += 256) h[i] = 0;
    __syncthreads();
    for (int e = blockIdx.x * blockDim.x + threadIdx.x; e < E; e += gridDim.x * blockDim.x) {
        int d = dst[e];
        d = ((unsigned)d < (unsigned)N) ? d : 0;
        atomicAdd(&h[min(d >> 10, 127)], 1);
    }
    __syncthreads();
    for (int i = threadIdx.x; i < 128; i += 256) if (h[i]) atomicAdd(&bcur[i], h[i]);
}

__global__ void k_bscan(int* __restrict__ bcur) {  // 1 block x 128 threads, exclusive scan
    __shared__ int sd[128];
    int t = threadIdx.x;
    int v = bcur[t];
    sd[t] = v;
    __syncthreads();
    for (int off = 1; off < 128; off <<= 1) {
        int x = (t >= off) ? sd[t - off] : 0;
        __syncthreads();
        sd[t] += x;
        __syncthreads();
    }
    bcur[t] = (t == 0) ? 0 : sd[t - 1];
}

// partition edges into bucket-ordered ebuf (uint2{src,dst}); also counts degrees (folded k_deg)
__global__ __launch_bounds__(256) void k_part(const int* __restrict__ src, const int* __restrict__ dst,
                                              int E, int N, int* __restrict__ bcur,
                                              int* __restrict__ cnt, uint2* __restrict__ ebuf) {
    __shared__ int lcnt[128], lbase[128];
    int t = threadIdx.x;
    int e0 = blockIdx.x * 4096;
    int s[16], d[16];
    for (int i = t; i < 128; i += 256) lcnt[i] = 0;
    __syncthreads();
#pragma unroll
    for (int j = 0; j < 16; j++) {
        int e = e0 + j * 256 + t;
        if (e < E) {
            int dd = dst[e];
            dd = ((unsigned)dd < (unsigned)N) ? dd : 0;  // clamp: consistent everywhere
            d[j] = dd;
            s[j] = src[e];
            atomicAdd(&lcnt[min(dd >> 10, 127)], 1);
            atomicAdd(&cnt[dd], 1);                      // folded degree count
        } else d[j] = -1;
    }
    __syncthreads();
    for (int i = t; i < 128; i += 256) lbase[i] = lcnt[i] ? atomicAdd(&bcur[i], lcnt[i]) : 0;
    __syncthreads();
    for (int i = t; i < 128; i += 256) lcnt[i] = 0;
    __syncthreads();
#pragma unroll
    for (int j = 0; j < 16; j++) {
        if (d[j] >= 0) {
            int bk = min(d[j] >> 10, 127);
            int pos = lbase[bk] + atomicAdd(&lcnt[bk], 1);
            ebuf[pos] = make_uint2((unsigned)s[j], (unsigned)d[j]);
        }
    }
}

__global__ void k_dinv(const int* __restrict__ cnt, int N, float* __restrict__ dinv) {
    int n = blockIdx.x * blockDim.x + threadIdx.x;
    if (n < N) dinv[n] = rsqrtf((float)(cnt[n] + 1));  // +1 self-loop
}

// ---------------- exclusive scan of cnt -> offs (2048 items/block) ----------------
__global__ void k_scan1(const int* __restrict__ cnt, int N,
                        int* __restrict__ offs, int* __restrict__ bsums) {
    __shared__ int sd[256];
    int t = threadIdx.x;
    int base = blockIdx.x * 2048 + t * 8;
    int v[8];
    int s = 0;
#pragma unroll
    for (int j = 0; j < 8; j++) {
        int i = base + j;
        v[j] = (i < N) ? cnt[i] : 0;
        s += v[j];
    }
    sd[t] = s;
    __syncthreads();
    for (int off = 1; off < 256; off <<= 1) {
        int x = (t >= off) ? sd[t - off] : 0;
        __syncthreads();
        sd[t] += x;
        __syncthreads();
    }
    int excl = (t == 0) ? 0 : sd[t - 1];
    if (t == 255) bsums[blockIdx.x] = sd[255];
    int run = excl;
#pragma unroll
    for (int j = 0; j < 8; j++) {
        int i = base + j;
        if (i < N) offs[i] = run;
        run += v[j];
    }
}

__global__ void k_scan2(int* __restrict__ bsums, int nb) {  // nb <= 64, one wave
    int t = threadIdx.x;
    int v = (t < nb) ? bsums[t] : 0;
    int orig = v;
    for (int off = 1; off < 64; off <<= 1) {
        int y = __shfl_up(v, off);
        if (t >= off) v += y;
    }
    if (t < nb) bsums[t] = v - orig;  // exclusive
}

__global__ void k_scan3(int* __restrict__ offs, int N, const int* __restrict__ bsums) {
    int i = blockIdx.x * blockDim.x + threadIdx.x;
    if (i < N) offs[i] += bsums[i >> 11];
}

// final CSR scatter; XCD-swizzled: region r of edge space handled only by blocks with blockIdx%8==r
// so each csr window is dirtied by a single XCD's L2 (write-merge instead of cross-XCD thrash).
__global__ __launch_bounds__(256) void k_scat2(const uint2* __restrict__ ebuf, int E,
                                               const int* __restrict__ offs, int* __restrict__ cursor,
                                               int* __restrict__ csr) {
    int r = blockIdx.x & 7;    // XCD under round-robin dispatch (perf heuristic only)
    int j = blockIdx.x >> 3;
    int Er = (E + 7) >> 3;
    int e0 = r * Er + j * 4096;
    int e1 = min(min((r + 1) * Er, E), e0 + 4096);
    for (int e = e0 + threadIdx.x; e < e1; e += 256) {
        uint2 p = ebuf[e];
        int d = p.y;
        int pos = atomicAdd(&cursor[d], 1);
        csr[offs[d] + pos] = (int)p.x;
    }
}

// ---------------- X -> fp16 ----------------
__global__ __launch_bounds__(256) void k_xh(const float4* __restrict__ X4, int M,
                                            uint2* __restrict__ Xh) {
    int i = blockIdx.x * 256 + threadIdx.x;
    if (i < M) {
        float4 v = X4[i];
        __half2 lo = __floats2half2_rn(v.x, v.y);
        __half2 hi = __floats2half2_rn(v.z, v.w);
        uint2 o;
        o.x = *(unsigned*)&lo;
        o.y = *(unsigned*)&hi;
        Xh[i] = o;
    }
}

// ---------------- layer-1 aggregation (fp16 gather): aggXh[n] = fp16(dn*(dn*X[n] + sum ds*X[s])) ----------------
// 16 threads per node, 4 dims each (uint2 = 4 halfs). Output is dn-prescaled: directly the MLP input t.
__global__ __launch_bounds__(256) void k_agg1(
        const uint2* __restrict__ Xh, const float* __restrict__ dinv,
        const int* __restrict__ offs, const int* __restrict__ cnt,
        const int* __restrict__ csr, int N, uint2* __restrict__ aggXh) {
    int tid = blockIdx.x * blockDim.x + threadIdx.x;
    int n = tid >> 4;
    int f = tid & 15;
    if (n >= N) return;
    float dn = dinv[n];
    float ax, ay, az, aw;
    {
        uint2 p = Xh[(size_t)n * 16 + f];
        __half2 lo = *(__half2*)&p.x, hi = *(__half2*)&p.y;
        ax = dn * __low2float(lo); ay = dn * __high2float(lo);
        az = dn * __low2float(hi); aw = dn * __high2float(hi);
    }
    int base = offs[n], deg = cnt[n];
    int j = 0;
    for (; j + 4 <= deg; j += 4) {
        int s0 = csr[base + j];
        int s1 = csr[base + j + 1];
        int s2 = csr[base + j + 2];
        int s3 = csr[base + j + 3];
        s0 = ((unsigned)s0 < (unsigned)N) ? s0 : 0;
        s1 = ((unsigned)s1 < (unsigned)N) ? s1 : 0;
        s2 = ((unsigned)s2 < (unsigned)N) ? s2 : 0;
        s3 = ((unsigned)s3 < (unsigned)N) ? s3 : 0;
        float w0 = dinv[s0], w1 = dinv[s1], w2 = dinv[s2], w3 = dinv[s3];
        uint2 p0 = Xh[(size_t)s0 * 16 + f];
        uint2 p1 = Xh[(size_t)s1 * 16 + f];
        uint2 p2 = Xh[(size_t)s2 * 16 + f];
        uint2 p3 = Xh[(size_t)s3 * 16 + f];
        __half2 l0 = *(__half2*)&p0.x, h0 = *(__half2*)&p0.y;
        __half2 l1 = *(__half2*)&p1.x, h1 = *(__half2*)&p1.y;
        __half2 l2 = *(__half2*)&p2.x, h2 = *(__half2*)&p2.y;
        __half2 l3 = *(__half2*)&p3.x, h3 = *(__half2*)&p3.y;
        ax += w0 * __low2float(l0) + w1 * __low2float(l1) + w2 * __low2float(l2) + w3 * __low2float(l3);
        ay += w0 * __high2float(l0) + w1 * __high2float(l1) + w2 * __high2float(l2) + w3 * __high2float(l3);
        az += w0 * __low2float(h0) + w1 * __low2float(h1) + w2 * __low2float(h2) + w3 * __low2float(h3);
        aw += w0 * __high2float(h0) + w1 * __high2float(h1) + w2 * __high2float(h2) + w3 * __high2float(h3);
    }
    for (; j < deg; j++) {
        int s0 = csr[base + j];
        s0 = ((unsigned)s0 < (unsigned)N) ? s0 : 0;
        float w0 = dinv[s0];
        uint2 p = Xh[(size_t)s0 * 16 + f];
        __half2 lo = *(__half2*)&p.x, hi = *(__half2*)&p.y;
        ax += w0 * __low2float(lo); ay += w0 * __high2float(lo);
        az += w0 * __low2float(hi); aw += w0 * __high2float(hi);
    }
    __half2 olo = __floats2half2_rn(dn * ax, dn * ay);
    __half2 ohi = __floats2half2_rn(dn * az, dn * aw);
    uint2 o;
    o.x = *(unsigned*)&olo;
    o.y = *(unsigned*)&ohi;
    aggXh[(size_t)n * 16 + f] = o;
}

// ---------------- MFMA MLP: h = elu(t@[Wn|Ws]+b); Zs = half(dn * h@Wf) ----------------
// aggXh is already dn-prescaled fp16 in A-fragment-friendly row-major: direct half8 loads.
__global__ __launch_bounds__(256) void k_mlp(
        const _Float16* __restrict__ aggXh, const float* __restrict__ dinv,
        const float* __restrict__ Wn, const float* __restrict__ bn,
        const float* __restrict__ Ws, const float* __restrict__ bs,
        const float* __restrict__ Wf, int N, _Float16* __restrict__ Zs) {
    __shared__ half8 sB2[32 * 64];
    __shared__ _Float16 Hbuf[4][16 * 136];

    const int l = threadIdx.x & 63;
    const int wid = threadIdx.x >> 6;
    const int q = l >> 4;
    const int n16 = l & 15;

    for (int e = threadIdx.x; e < 32 * 64; e += 256) {
        int tile = e >> 6, le = e & 63;
        int kt = tile >> 2, nt = tile & 3;
        int qq = le >> 4, nn = le & 15;
        half8 v;
#pragma unroll
        for (int j = 0; j < 8; j++)
            v[j] = (_Float16)Wf[(kt * 32 + qq * 8 + j) * 64 + nt * 16 + nn];
        sB2[e] = v;
    }
    __syncthreads();

    half8 w1n[8], w1s[8];
#pragma unroll
    for (int nt = 0; nt < 8; nt++) {
        half8 a, b;
#pragma unroll
        for (int j = 0; j < 8; j++) {
            a[j] = (_Float16)Wn[(q * 8 + j) * 128 + nt * 16 + n16];
            b[j] = (_Float16)Ws[(q * 8 + j) * 128 + nt * 16 + n16];
        }
        w1n[nt] = a;
        w1s[nt] = b;
    }
    float bnr[8], bsr[8];
#pragma unroll
    for (int nt = 0; nt < 8; nt++) {
        bnr[nt] = bn[nt * 16 + n16];
        bsr[nt] = bs[nt * 16 + n16];
    }

    const int ntiles = (N + 15) >> 4;
    const int nw = gridDim.x * 4;
    _Float16* Hw = Hbuf[wid];

    for (int tile = blockIdx.x * 4 + wid; tile < ntiles; tile += nw) {
        int nb = tile << 4;
        int nodeA = nb + n16;
        if (nodeA >= N) nodeA = N - 1;
        float dn = dinv[nodeA];
        half8 an = *(const half8*)&aggXh[(size_t)nodeA * 64 + q * 8];
        half8 as = *(const half8*)&aggXh[(size_t)nodeA * 64 + 32 + q * 8];

        f32x4 Y[4];
#pragma unroll
        for (int i = 0; i < 4; i++) Y[i] = (f32x4){0.f, 0.f, 0.f, 0.f};

        f32x4 c1[8];
#pragma unroll
        for (int nt = 0; nt < 8; nt++)
            c1[nt] = __builtin_amdgcn_mfma_f32_16x16x32_f16(an, w1n[nt], (f32x4){0.f, 0.f, 0.f, 0.f}, 0, 0, 0);
#pragma unroll
        for (int nt = 0; nt < 8; nt++) {
#pragma unroll
            for (int r = 0; r < 4; r++) {
                float v = c1[nt][r] + bnr[nt];
                v = v > 0.f ? v : expm1f(v);
                Hw[(q * 4 + r) * 136 + nt * 16 + n16] = (_Float16)v;
            }
        }
#pragma unroll
        for (int kt = 0; kt < 4; kt++) {
            half8 ha = *(const half8*)&Hw[n16 * 136 + kt * 32 + q * 8];
#pragma unroll
            for (int nt2 = 0; nt2 < 4; nt2++)
                Y[nt2] = __builtin_amdgcn_mfma_f32_16x16x32_f16(ha, sB2[(kt * 4 + nt2) * 64 + l], Y[nt2], 0, 0, 0);
        }
#pragma unroll
        for (int nt = 0; nt < 8; nt++)
            c1[nt] = __builtin_amdgcn_mfma_f32_16x16x32_f16(as, w1s[nt], (f32x4){0.f, 0.f, 0.f, 0.f}, 0, 0, 0);
#pragma unroll
        for (int nt = 0; nt < 8; nt++) {
#pragma unroll
            for (int r = 0; r < 4; r++) {
                float v = c1[nt][r] + bsr[nt];
                v = v > 0.f ? v : expm1f(v);
                Hw[(q * 4 + r) * 136 + nt * 16 + n16] = (_Float16)v;
            }
        }
#pragma unroll
        for (int kt = 0; kt < 4; kt++) {
            half8 ha = *(const half8*)&Hw[n16 * 136 + kt * 32 + q * 8];
#pragma unroll
            for (int nt2 = 0; nt2 < 4; nt2++)
                Y[nt2] = __builtin_amdgcn_mfma_f32_16x16x32_f16(ha, sB2[((4 + kt) * 4 + nt2) * 64 + l], Y[nt2], 0, 0, 0);
        }
        float dnr[4];
#pragma unroll
        for (int r = 0; r < 4; r++) dnr[r] = __shfl(dn, q * 4 + r);
#pragma unroll
        for (int r = 0; r < 4; r++) {
            int node = nb + q * 4 + r;
            if (node < N) {
#pragma unroll
                for (int nt2 = 0; nt2 < 4; nt2++)
                    Zs[(size_t)node * 64 + nt2 * 16 + n16] = (_Float16)(dnr[r] * Y[nt2][r]);
            }
        }
    }
}

// ---------------- layer-2 aggregation + bias + softmax ----------------
__global__ __launch_bounds__(256) void k_agg2(
        const uint2* __restrict__ Zu,  // dense rows: 16 uint2 per node
        const float* __restrict__ dinv,
        const int* __restrict__ offs, const int* __restrict__ cnt,
        const int* __restrict__ csr, const float4* __restrict__ bias4,
        int N, float4* __restrict__ out4) {
    int tid = blockIdx.x * blockDim.x + threadIdx.x;
    int n = tid >> 4;
    int f = tid & 15;
    if (n >= N) return;
    float ax = 0.f, ay = 0.f, az = 0.f, aw = 0.f;
    {
        uint2 p = Zu[(size_t)n * 16 + f];
        __half2 lo = *(__half2*)&p.x, hi = *(__half2*)&p.y;
        ax = __low2float(lo); ay = __high2float(lo);
        az = __low2float(hi); aw = __high2float(hi);
    }
    int base = offs[n], deg = cnt[n];
    int j = 0;
    for (; j + 4 <= deg; j += 4) {
        int s0 = csr[base + j];
        int s1 = csr[base + j + 1];
        int s2 = csr[base + j + 2];
        int s3 = csr[base + j + 3];
        s0 = ((unsigned)s0 < (unsigned)N) ? s0 : 0;
        s1 = ((unsigned)s1 < (unsigned)N) ? s1 : 0;
        s2 = ((unsigned)s2 < (unsigned)N) ? s2 : 0;
        s3 = ((unsigned)s3 < (unsigned)N) ? s3 : 0;
        uint2 p0 = Zu[(size_t)s0 * 16 + f];
        uint2 p1 = Zu[(size_t)s1 * 16 + f];
        uint2 p2 = Zu[(size_t)s2 * 16 + f];
        uint2 p3 = Zu[(size_t)s3 * 16 + f];
#pragma unroll
        for (int k = 0; k < 4; k++) {
            uint2 p = (k == 0) ? p0 : (k == 1) ? p1 : (k == 2) ? p2 : p3;
            __half2 lo = *(__half2*)&p.x, hi = *(__half2*)&p.y;
            ax += __low2float(lo); ay += __high2float(lo);
            az += __low2float(hi); aw += __high2float(hi);
        }
    }
    for (; j < deg; j++) {
        int s0 = csr[base + j];
        s0 = ((unsigned)s0 < (unsigned)N) ? s0 : 0;
        uint2 p = Zu[(size_t)s0 * 16 + f];
        __half2 lo = *(__half2*)&p.x, hi = *(__half2*)&p.y;
        ax += __low2float(lo); ay += __high2float(lo);
        az += __low2float(hi); aw += __high2float(hi);
    }
    float dn = dinv[n];
    float4 b = bias4[f];
    ax = dn * ax + b.x; ay = dn * ay + b.y; az = dn * az + b.z; aw = dn * aw + b.w;
    float mx = fmaxf(fmaxf(ax, ay), fmaxf(az, aw));
    for (int o = 8; o >= 1; o >>= 1) mx = fmaxf(mx, __shfl_xor(mx, o));
    float ex = expf(ax - mx), ey = expf(ay - mx), ez = expf(az - mx), ew = expf(aw - mx);
    float sm = ex + ey + ez + ew;
    for (int o = 8; o >= 1; o >>= 1) sm += __shfl_xor(sm, o);
    float inv = 1.f / sm;
    out4[(size_t)n * 16 + f] = make_float4(ex * inv, ey * inv, ez * inv, ew * inv);
}

extern "C" void kernel_launch(void* const* d_in, const int* in_sizes, int n_in,
                              void* d_out, int out_size, void* d_ws, size_t ws_size,
                              hipStream_t stream) {
    const float* X = (const float*)d_in[0];
    const int* ei = (const int*)d_in[1];
    // d_in[2] = batch (unused)
    const float* Wn = (const float*)d_in[3];
    const float* bn = (const float*)d_in[4];
    const float* Ws = (const float*)d_in[5];
    const float* bs = (const float*)d_in[6];
    const float* Wf = (const float*)d_in[7];
    const float* bfu = (const float*)d_in[8];

    const int N = in_sizes[2];        // 100000
    const int E = in_sizes[1] / 2;    // 1600000
    const int* src = ei;
    const int* dst = ei + E;

    // workspace layout (128-aligned); total ~33.6 MB (proven-safe footprint)
    char* ws = (char*)d_ws;
    int* cnt      = (int*)(ws + 0);            // 400000 -> pad 400128
    int* cursor   = (int*)(ws + 400128);       // 400000 -> pad 800256
    int* bcur     = (int*)(ws + 800256);       // 512    -> 800768
    float* dinv   = (float*)(ws + 800768);     // 400000 -> 1200768
    int* offs     = (int*)(ws + 1200768);      // 400000 -> 1600768
    int* bsums    = (int*)(ws + 1600768);      // 256    -> 1601024
    int* csr      = (int*)(ws + 1601024);      // 6400000 -> 8001024
    // slot A [8001024, 20801024): ebuf (part/scat2), then aggXh (agg1 -> mlp)
    uint2* ebuf   = (uint2*)(ws + 8001024);
    uint2* aggXh  = (uint2*)(ws + 8001024);
    // slot B [20801024, 33601024): Xh (xh -> agg1), then Zs (mlp -> agg2)
    uint2* Xh     = (uint2*)(ws + 20801024);
    _Float16* Zs  = (_Float16*)(ws + 20801024);

    hipMemsetAsync(ws, 0, 800768, stream);  // zero cnt + cursor + bcur

    int nbl = (N + 255) / 256;
    int nb1 = (N + 2047) / 2048;     // 49 <= 64
    int pbl = (E + 4095) / 4096;     // 391 blocks, 4096 edges each
    int sbl = 8 * (((E + 7) / 8 + 4095) / 4096);  // 8 regions x 49 blocks = 392

    k_bhist<<<pbl, 256, 0, stream>>>(dst, E, N, bcur);
    k_bscan<<<1, 128, 0, stream>>>(bcur);
    k_part<<<pbl, 256, 0, stream>>>(src, dst, E, N, bcur, cnt, ebuf);
    k_dinv<<<nbl, 256, 0, stream>>>(cnt, N, dinv);
    k_scan1<<<nb1, 256, 0, stream>>>(cnt, N, offs, bsums);
    k_scan2<<<1, 64, 0, stream>>>(bsums, nb1);
    k_scan3<<<nbl, 256, 0, stream>>>(offs, N, bsums);
    k_scat2<<<sbl, 256, 0, stream>>>(ebuf, E, offs, cursor, csr);

    int M = N * 16;
    k_xh<<<(M + 255) / 256, 256, 0, stream>>>((const float4*)X, M, Xh);

    int gbl = (M + 255) / 256;  // thread-per-(node, chunk)
    k_agg1<<<gbl, 256, 0, stream>>>(Xh, dinv, offs, cnt, csr, N, aggXh);
    k_mlp<<<512, 256, 0, stream>>>((const _Float16*)aggXh, dinv, Wn, bn, Ws, bs, Wf, N, Zs);
    k_agg2<<<gbl, 256, 0, stream>>>((const uint2*)Zs, dinv, offs, cnt, csr,
                                    (const float4*)bfu, N, (float4*)d_out);
}

// Round 8
// 340.436 us; speedup vs baseline: 3.2442x; 1.0242x over previous
//
#include <hip/hip_runtime.h>
#include <hip/hip_fp16.h>

using half8 = __attribute__((ext_vector_type(8))) _Float16;
using f32x4 = __attribute__((ext_vector_type(4))) float;

// ============ bucketed CSR build, XCD-privatized ============
// bucket b = min(dst >> 10, 127); region r = blockIdx%8 slice of the edge array
// (round-robin dispatch => region r runs on XCD r; perf heuristic only).
// ebuf order: bucket-major, region-minor => each (b,r) sub-chunk written by one XCD.

__global__ __launch_bounds__(256) void k_bhist(const int* __restrict__ dst, int E, int Er, int N,
                                               int* __restrict__ bhist) {
    __shared__ int h[128];
    for (int i = threadIdx.x; i < 128; i += 256) h[i] = 0;
    __syncthreads();
    int r = blockIdx.x & 7, j = blockIdx.x >> 3;
    int e0 = r * Er + j * 4096;
    int e1 = min(min((r + 1) * Er, E), e0 + 4096);
    for (int e = e0 + threadIdx.x; e < e1; e += 256) {
        int d = dst[e];
        d = ((unsigned)d < (unsigned)N) ? d : 0;
        atomicAdd(&h[min(d >> 10, 127)], 1);
    }
    __syncthreads();
    for (int i = threadIdx.x; i < 128; i += 256)
        if (h[i]) atomicAdd(&bhist[i * 8 + r], h[i]);
}

__global__ void k_bscan(int* __restrict__ bcur) {  // 1 block x 1024, exclusive scan
    __shared__ int sd[1024];
    int t = threadIdx.x;
    int v = bcur[t];
    sd[t] = v;
    __syncthreads();
    for (int off = 1; off < 1024; off <<= 1) {
        int x = (t >= off) ? sd[t - off] : 0;
        __syncthreads();
        sd[t] += x;
        __syncthreads();
    }
    bcur[t] = sd[t] - v;  // exclusive
}

// partition edges into (bucket,region)-ordered ebuf; writes XCD-private
__global__ __launch_bounds__(256) void k_part(const int* __restrict__ src, const int* __restrict__ dst,
                                              int E, int Er, int N, int* __restrict__ bcur,
                                              uint2* __restrict__ ebuf) {
    __shared__ int lcnt[128], lbase[128];
    int t = threadIdx.x;
    int r = blockIdx.x & 7, jb = blockIdx.x >> 3;
    int e0 = r * Er + jb * 4096;
    int e1 = min(min((r + 1) * Er, E), e0 + 4096);
    int s[16], d[16];
    for (int i = t; i < 128; i += 256) lcnt[i] = 0;
    __syncthreads();
#pragma unroll
    for (int j = 0; j < 16; j++) {
        int e = e0 + j * 256 + t;
        if (e < e1) {
            int dd = dst[e];
            dd = ((unsigned)dd < (unsigned)N) ? dd : 0;  // clamp: consistent everywhere
            d[j] = dd;
            s[j] = src[e];
            atomicAdd(&lcnt[min(dd >> 10, 127)], 1);
        } else d[j] = -1;
    }
    __syncthreads();
    for (int i = t; i < 128; i += 256)
        lbase[i] = lcnt[i] ? atomicAdd(&bcur[i * 8 + r], lcnt[i]) : 0;
    __syncthreads();
    for (int i = t; i < 128; i += 256) lcnt[i] = 0;
    __syncthreads();
#pragma unroll
    for (int j = 0; j < 16; j++) {
        if (d[j] >= 0) {
            int bk = min(d[j] >> 10, 127);
            int pos = lbase[bk] + atomicAdd(&lcnt[bk], 1);
            ebuf[pos] = make_uint2((unsigned)s[j], (unsigned)d[j]);
        }
    }
}

// degree count over bucket-ordered ebuf; XCD-swizzled => cnt atomics hit ~50KB XCD-local windows
__global__ __launch_bounds__(256) void k_deg2(const uint2* __restrict__ ebuf, int E, int Er,
                                              int* __restrict__ cnt) {
    int r = blockIdx.x & 7, j = blockIdx.x >> 3;
    int e0 = r * Er + j * 4096;
    int e1 = min(min((r + 1) * Er, E), e0 + 4096);
    for (int e = e0 + threadIdx.x; e < e1; e += 256)
        atomicAdd(&cnt[ebuf[e].y], 1);
}

// ---------------- exclusive scan of cnt -> offs (+ fused dinv) ----------------
__global__ void k_scan1(const int* __restrict__ cnt, int N,
                        int* __restrict__ offs, int* __restrict__ bsums,
                        float* __restrict__ dinv) {
    __shared__ int sd[256];
    int t = threadIdx.x;
    int base = blockIdx.x * 2048 + t * 8;
    int v[8];
    int s = 0;
#pragma unroll
    for (int j = 0; j < 8; j++) {
        int i = base + j;
        v[j] = (i < N) ? cnt[i] : 0;
        if (i < N) dinv[i] = rsqrtf((float)(v[j] + 1));  // +1 self-loop
        s += v[j];
    }
    sd[t] = s;
    __syncthreads();
    for (int off = 1; off < 256; off <<= 1) {
        int x = (t >= off) ? sd[t - off] : 0;
        __syncthreads();
        sd[t] += x;
        __syncthreads();
    }
    int excl = (t == 0) ? 0 : sd[t - 1];
    if (t == 255) bsums[blockIdx.x] = sd[255];
    int run = excl;
#pragma unroll
    for (int j = 0; j < 8; j++) {
        int i = base + j;
        if (i < N) offs[i] = run;
        run += v[j];
    }
}

__global__ void k_scan2(int* __restrict__ bsums, int nb) {  // nb <= 64, one wave
    int t = threadIdx.x;
    int v = (t < nb) ? bsums[t] : 0;
    int orig = v;
    for (int off = 1; off < 64; off <<= 1) {
        int y = __shfl_up(v, off);
        if (t >= off) v += y;
    }
    if (t < nb) bsums[t] = v - orig;  // exclusive
}

__global__ void k_scan3(int* __restrict__ offs, int N, const int* __restrict__ bsums) {
    int i = blockIdx.x * blockDim.x + threadIdx.x;
    if (i < N) offs[i] += bsums[i >> 11];
}

// final CSR scatter; XCD-swizzled (bucket-ordered ebuf => csr windows XCD-private)
__global__ __launch_bounds__(256) void k_scat2(const uint2* __restrict__ ebuf, int E, int Er,
                                               const int* __restrict__ offs, int* __restrict__ cursor,
                                               int* __restrict__ csr) {
    int r = blockIdx.x & 7, j = blockIdx.x >> 3;
    int e0 = r * Er + j * 4096;
    int e1 = min(min((r + 1) * Er, E), e0 + 4096);
    for (int e = e0 + threadIdx.x; e < e1; e += 256) {
        uint2 p = ebuf[e];
        int d = p.y;
        int pos = atomicAdd(&cursor[d], 1);
        csr[offs[d] + pos] = (int)p.x;
    }
}

// ---------------- X -> fp16 ----------------
__global__ __launch_bounds__(256) void k_xh(const float4* __restrict__ X4, int M,
                                            uint2* __restrict__ Xh) {
    int i = blockIdx.x * 256 + threadIdx.x;
    if (i < M) {
        float4 v = X4[i];
        __half2 lo = __floats2half2_rn(v.x, v.y);
        __half2 hi = __floats2half2_rn(v.z, v.w);
        uint2 o;
        o.x = *(unsigned*)&lo;
        o.y = *(unsigned*)&hi;
        Xh[i] = o;
    }
}

// ---------------- layer-1 aggregation (fp16 gather): aggXh[n] = fp16(dn*(dn*X[n] + sum ds*X[s])) ----------------
__global__ __launch_bounds__(256) void k_agg1(
        const uint2* __restrict__ Xh, const float* __restrict__ dinv,
        const int* __restrict__ offs, const int* __restrict__ cnt,
        const int* __restrict__ csr, int N, uint2* __restrict__ aggXh) {
    int tid = blockIdx.x * blockDim.x + threadIdx.x;
    int n = tid >> 4;
    int f = tid & 15;
    if (n >= N) return;
    float dn = dinv[n];
    float ax, ay, az, aw;
    {
        uint2 p = Xh[(size_t)n * 16 + f];
        __half2 lo = *(__half2*)&p.x, hi = *(__half2*)&p.y;
        ax = dn * __low2float(lo); ay = dn * __high2float(lo);
        az = dn * __low2float(hi); aw = dn * __high2float(hi);
    }
    int base = offs[n], deg = cnt[n];
    int j = 0;
    for (; j + 4 <= deg; j += 4) {
        int s0 = csr[base + j];
        int s1 = csr[base + j + 1];
        int s2 = csr[base + j + 2];
        int s3 = csr[base + j + 3];
        s0 = ((unsigned)s0 < (unsigned)N) ? s0 : 0;
        s1 = ((unsigned)s1 < (unsigned)N) ? s1 : 0;
        s2 = ((unsigned)s2 < (unsigned)N) ? s2 : 0;
        s3 = ((unsigned)s3 < (unsigned)N) ? s3 : 0;
        float w0 = dinv[s0], w1 = dinv[s1], w2 = dinv[s2], w3 = dinv[s3];
        uint2 p0 = Xh[(size_t)s0 * 16 + f];
        uint2 p1 = Xh[(size_t)s1 * 16 + f];
        uint2 p2 = Xh[(size_t)s2 * 16 + f];
        uint2 p3 = Xh[(size_t)s3 * 16 + f];
        __half2 l0 = *(__half2*)&p0.x, h0 = *(__half2*)&p0.y;
        __half2 l1 = *(__half2*)&p1.x, h1 = *(__half2*)&p1.y;
        __half2 l2 = *(__half2*)&p2.x, h2 = *(__half2*)&p2.y;
        __half2 l3 = *(__half2*)&p3.x, h3 = *(__half2*)&p3.y;
        ax += w0 * __low2float(l0) + w1 * __low2float(l1) + w2 * __low2float(l2) + w3 * __low2float(l3);
        ay += w0 * __high2float(l0) + w1 * __high2float(l1) + w2 * __high2float(l2) + w3 * __high2float(l3);
        az += w0 * __low2float(h0) + w1 * __low2float(h1) + w2 * __low2float(h2) + w3 * __low2float(h3);
        aw += w0 * __high2float(h0) + w1 * __high2float(h1) + w2 * __high2float(h2) + w3 * __high2float(h3);
    }
    for (; j < deg; j++) {
        int s0 = csr[base + j];
        s0 = ((unsigned)s0 < (unsigned)N) ? s0 : 0;
        float w0 = dinv[s0];
        uint2 p = Xh[(size_t)s0 * 16 + f];
        __half2 lo = *(__half2*)&p.x, hi = *(__half2*)&p.y;
        ax += w0 * __low2float(lo); ay += w0 * __high2float(lo);
        az += w0 * __low2float(hi); aw += w0 * __high2float(hi);
    }
    __half2 olo = __floats2half2_rn(dn * ax, dn * ay);
    __half2 ohi = __floats2half2_rn(dn * az, dn * aw);
    uint2 o;
    o.x = *(unsigned*)&olo;
    o.y = *(unsigned*)&ohi;
    aggXh[(size_t)n * 16 + f] = o;
}

// ---------------- MFMA MLP: h = elu(t@[Wn|Ws]+b); Zs = half(dn * h@Wf) ----------------
__global__ __launch_bounds__(256) void k_mlp(
        const _Float16* __restrict__ aggXh, const float* __restrict__ dinv,
        const float* __restrict__ Wn, const float* __restrict__ bn,
        const float* __restrict__ Ws, const float* __restrict__ bs,
        const float* __restrict__ Wf, int N, _Float16* __restrict__ Zs) {
    __shared__ half8 sB2[32 * 64];
    __shared__ _Float16 Hbuf[4][16 * 136];

    const int l = threadIdx.x & 63;
    const int wid = threadIdx.x >> 6;
    const int q = l >> 4;
    const int n16 = l & 15;

    for (int e = threadIdx.x; e < 32 * 64; e += 256) {
        int tile = e >> 6, le = e & 63;
        int kt = tile >> 2, nt = tile & 3;
        int qq = le >> 4, nn = le & 15;
        half8 v;
#pragma unroll
        for (int j = 0; j < 8; j++)
            v[j] = (_Float16)Wf[(kt * 32 + qq * 8 + j) * 64 + nt * 16 + nn];
        sB2[e] = v;
    }
    __syncthreads();

    half8 w1n[8], w1s[8];
#pragma unroll
    for (int nt = 0; nt < 8; nt++) {
        half8 a, b;
#pragma unroll
        for (int j = 0; j < 8; j++) {
            a[j] = (_Float16)Wn[(q * 8 + j) * 128 + nt * 16 + n16];
            b[j] = (_Float16)Ws[(q * 8 + j) * 128 + nt * 16 + n16];
        }
        w1n[nt] = a;
        w1s[nt] = b;
    }
    float bnr[8], bsr[8];
#pragma unroll
    for (int nt = 0; nt < 8; nt++) {
        bnr[nt] = bn[nt * 16 + n16];
        bsr[nt] = bs[nt * 16 + n16];
    }

    const int ntiles = (N + 15) >> 4;
    const int nw = gridDim.x * 4;
    _Float16* Hw = Hbuf[wid];

    for (int tile = blockIdx.x * 4 + wid; tile < ntiles; tile += nw) {
        int nb = tile << 4;
        int nodeA = nb + n16;
        if (nodeA >= N) nodeA = N - 1;
        float dn = dinv[nodeA];
        half8 an = *(const half8*)&aggXh[(size_t)nodeA * 64 + q * 8];
        half8 as = *(const half8*)&aggXh[(size_t)nodeA * 64 + 32 + q * 8];

        f32x4 Y[4];
#pragma unroll
        for (int i = 0; i < 4; i++) Y[i] = (f32x4){0.f, 0.f, 0.f, 0.f};

        f32x4 c1[8];
#pragma unroll
        for (int nt = 0; nt < 8; nt++)
            c1[nt] = __builtin_amdgcn_mfma_f32_16x16x32_f16(an, w1n[nt], (f32x4){0.f, 0.f, 0.f, 0.f}, 0, 0, 0);
#pragma unroll
        for (int nt = 0; nt < 8; nt++) {
#pragma unroll
            for (int r = 0; r < 4; r++) {
                float v = c1[nt][r] + bnr[nt];
                v = v > 0.f ? v : expm1f(v);
                Hw[(q * 4 + r) * 136 + nt * 16 + n16] = (_Float16)v;
            }
        }
#pragma unroll
        for (int kt = 0; kt < 4; kt++) {
            half8 ha = *(const half8*)&Hw[n16 * 136 + kt * 32 + q * 8];
#pragma unroll
            for (int nt2 = 0; nt2 < 4; nt2++)
                Y[nt2] = __builtin_amdgcn_mfma_f32_16x16x32_f16(ha, sB2[(kt * 4 + nt2) * 64 + l], Y[nt2], 0, 0, 0);
        }
#pragma unroll
        for (int nt = 0; nt < 8; nt++)
            c1[nt] = __builtin_amdgcn_mfma_f32_16x16x32_f16(as, w1s[nt], (f32x4){0.f, 0.f, 0.f, 0.f}, 0, 0, 0);
#pragma unroll
        for (int nt = 0; nt < 8; nt++) {
#pragma unroll
            for (int r = 0; r < 4; r++) {
                float v = c1[nt][r] + bsr[nt];
                v = v > 0.f ? v : expm1f(v);
                Hw[(q * 4 + r) * 136 + nt * 16 + n16] = (_Float16)v;
            }
        }
#pragma unroll
        for (int kt = 0; kt < 4; kt++) {
            half8 ha = *(const half8*)&Hw[n16 * 136 + kt * 32 + q * 8];
#pragma unroll
            for (int nt2 = 0; nt2 < 4; nt2++)
                Y[nt2] = __builtin_amdgcn_mfma_f32_16x16x32_f16(ha, sB2[((4 + kt) * 4 + nt2) * 64 + l], Y[nt2], 0, 0, 0);
        }
        float dnr[4];
#pragma unroll
        for (int r = 0; r < 4; r++) dnr[r] = __shfl(dn, q * 4 + r);
#pragma unroll
        for (int r = 0; r < 4; r++) {
            int node = nb + q * 4 + r;
            if (node < N) {
#pragma unroll
                for (int nt2 = 0; nt2 < 4; nt2++)
                    Zs[(size_t)node * 64 + nt2 * 16 + n16] = (_Float16)(dnr[r] * Y[nt2][r]);
            }
        }
    }
}

// ---------------- layer-2 aggregation + bias + softmax ----------------
__global__ __launch_bounds__(256) void k_agg2(
        const uint2* __restrict__ Zu, const float* __restrict__ dinv,
        const int* __restrict__ offs, const int* __restrict__ cnt,
        const int* __restrict__ csr, const float4* __restrict__ bias4,
        int N, float4* __restrict__ out4) {
    int tid = blockIdx.x * blockDim.x + threadIdx.x;
    int n = tid >> 4;
    int f = tid & 15;
    if (n >= N) return;
    float ax = 0.f, ay = 0.f, az = 0.f, aw = 0.f;
    {
        uint2 p = Zu[(size_t)n * 16 + f];
        __half2 lo = *(__half2*)&p.x, hi = *(__half2*)&p.y;
        ax = __low2float(lo); ay = __high2float(lo);
        az = __low2float(hi); aw = __high2float(hi);
    }
    int base = offs[n], deg = cnt[n];
    int j = 0;
    for (; j + 4 <= deg; j += 4) {
        int s0 = csr[base + j];
        int s1 = csr[base + j + 1];
        int s2 = csr[base + j + 2];
        int s3 = csr[base + j + 3];
        s0 = ((unsigned)s0 < (unsigned)N) ? s0 : 0;
        s1 = ((unsigned)s1 < (unsigned)N) ? s1 : 0;
        s2 = ((unsigned)s2 < (unsigned)N) ? s2 : 0;
        s3 = ((unsigned)s3 < (unsigned)N) ? s3 : 0;
        uint2 p0 = Zu[(size_t)s0 * 16 + f];
        uint2 p1 = Zu[(size_t)s1 * 16 + f];
        uint2 p2 = Zu[(size_t)s2 * 16 + f];
        uint2 p3 = Zu[(size_t)s3 * 16 + f];
#pragma unroll
        for (int k = 0; k < 4; k++) {
            uint2 p = (k == 0) ? p0 : (k == 1) ? p1 : (k == 2) ? p2 : p3;
            __half2 lo = *(__half2*)&p.x, hi = *(__half2*)&p.y;
            ax += __low2float(lo); ay += __high2float(lo);
            az += __low2float(hi); aw += __high2float(hi);
        }
    }
    for (; j < deg; j++) {
        int s0 = csr[base + j];
        s0 = ((unsigned)s0 < (unsigned)N) ? s0 : 0;
        uint2 p = Zu[(size_t)s0 * 16 + f];
        __half2 lo = *(__half2*)&p.x, hi = *(__half2*)&p.y;
        ax += __low2float(lo); ay += __high2float(lo);
        az += __low2float(hi); aw += __high2float(hi);
    }
    float dn = dinv[n];
    float4 b = bias4[f];
    ax = dn * ax + b.x; ay = dn * ay + b.y; az = dn * az + b.z; aw = dn * aw + b.w;
    float mx = fmaxf(fmaxf(ax, ay), fmaxf(az, aw));
    for (int o = 8; o >= 1; o >>= 1) mx = fmaxf(mx, __shfl_xor(mx, o));
    float ex = expf(ax - mx), ey = expf(ay - mx), ez = expf(az - mx), ew = expf(aw - mx);
    float sm = ex + ey + ez + ew;
    for (int o = 8; o >= 1; o >>= 1) sm += __shfl_xor(sm, o);
    float inv = 1.f / sm;
    out4[(size_t)n * 16 + f] = make_float4(ex * inv, ey * inv, ez * inv, ew * inv);
}

extern "C" void kernel_launch(void* const* d_in, const int* in_sizes, int n_in,
                              void* d_out, int out_size, void* d_ws, size_t ws_size,
                              hipStream_t stream) {
    const float* X = (const float*)d_in[0];
    const int* ei = (const int*)d_in[1];
    // d_in[2] = batch (unused)
    const float* Wn = (const float*)d_in[3];
    const float* bn = (const float*)d_in[4];
    const float* Ws = (const float*)d_in[5];
    const float* bs = (const float*)d_in[6];
    const float* Wf = (const float*)d_in[7];
    const float* bfu = (const float*)d_in[8];

    const int N = in_sizes[2];        // 100000
    const int E = in_sizes[1] / 2;    // 1600000
    const int* src = ei;
    const int* dst = ei + E;

    // workspace layout (128-aligned); total ~33.6 MB (proven-safe footprint)
    char* ws = (char*)d_ws;
    int* cnt      = (int*)(ws + 0);            // 400000 -> pad 400128
    int* cursor   = (int*)(ws + 400128);       // 400000 -> pad 800256
    int* bcur     = (int*)(ws + 800256);       // 1024*4 -> 804352
    float* dinv   = (float*)(ws + 804352);     // 400000 -> 1204352
    int* offs     = (int*)(ws + 1204352);      // 400000 -> 1604352
    int* bsums    = (int*)(ws + 1604352);      // 256    -> 1604608
    int* csr      = (int*)(ws + 1604608);      // 6400000 -> 8004608
    // slot A: ebuf (part/deg2/scat2), then aggXh (agg1 -> mlp)
    uint2* ebuf   = (uint2*)(ws + 8004608);    // 12800000 -> 20804608
    uint2* aggXh  = (uint2*)(ws + 8004608);
    // slot B: Xh (xh -> agg1), then Zs (mlp -> agg2)
    uint2* Xh     = (uint2*)(ws + 20804608);   // 12800000 -> 33604608 total
    _Float16* Zs  = (_Float16*)(ws + 20804608);

    hipMemsetAsync(ws, 0, 804352, stream);  // zero cnt + cursor + bcur

    int nbl = (N + 255) / 256;
    int nb1 = (N + 2047) / 2048;          // 49 <= 64
    int Er = (E + 7) / 8;                 // edges per XCD region
    int sbl = 8 * ((Er + 4095) / 4096);   // swizzled grid

    k_bhist<<<sbl, 256, 0, stream>>>(dst, E, Er, N, bcur);
    k_bscan<<<1, 1024, 0, stream>>>(bcur);
    k_part<<<sbl, 256, 0, stream>>>(src, dst, E, Er, N, bcur, ebuf);
    k_deg2<<<sbl, 256, 0, stream>>>(ebuf, E, Er, cnt);
    k_scan1<<<nb1, 256, 0, stream>>>(cnt, N, offs, bsums, dinv);
    k_scan2<<<1, 64, 0, stream>>>(bsums, nb1);
    k_scan3<<<nbl, 256, 0, stream>>>(offs, N, bsums);
    k_scat2<<<sbl, 256, 0, stream>>>(ebuf, E, Er, offs, cursor, csr);

    int M = N * 16;
    k_xh<<<(M + 255) / 256, 256, 0, stream>>>((const float4*)X, M, Xh);

    int gbl = (M + 255) / 256;  // thread-per-(node, chunk)
    k_agg1<<<gbl, 256, 0, stream>>>(Xh, dinv, offs, cnt, csr, N, aggXh);
    k_mlp<<<512, 256, 0, stream>>>((const _Float16*)aggXh, dinv, Wn, bn, Ws, bs, Wf, N, Zs);
    k_agg2<<<gbl, 256, 0, stream>>>((const uint2*)Zs, dinv, offs, cnt, csr,
                                    (const float4*)bfu, N, (float4*)d_out);
}

// Round 9
// 264.794 us; speedup vs baseline: 4.1710x; 1.2857x over previous
//
#include <hip/hip_runtime.h>
#include <hip/hip_fp16.h>

using half8 = __attribute__((ext_vector_type(8))) _Float16;
using f32x4 = __attribute__((ext_vector_type(4))) float;

// ============ bucketed CSR build ============
// bucket b = dst >> 8 (256 nodes/bucket, NB=391); region r = blockIdx%8 edge slice.
// ebuf order: bucket-major, region-minor. One block later owns one whole bucket.

__global__ __launch_bounds__(256) void k_bhist(const int* __restrict__ dst, int E, int Er, int N,
                                               int* __restrict__ bhist) {
    extern __shared__ int h[];  // NB ints
    const int NB = (N + 255) >> 8;
    for (int i = threadIdx.x; i < NB; i += 256) h[i] = 0;
    __syncthreads();
    int r = blockIdx.x & 7, j = blockIdx.x >> 3;
    int e0 = r * Er + j * 4096;
    int e1 = min(min((r + 1) * Er, E), e0 + 4096);
    for (int e = e0 + threadIdx.x; e < e1; e += 256) {
        int d = dst[e];
        d = ((unsigned)d < (unsigned)N) ? d : 0;
        atomicAdd(&h[d >> 8], 1);
    }
    __syncthreads();
    for (int i = threadIdx.x; i < NB; i += 256)
        if (h[i]) atomicAdd(&bhist[i * 8 + r], h[i]);
}

// exclusive scan of bcur[M], M = NB*8 <= 4096; also emit pristine bucket starts
__global__ void k_bscan(int* __restrict__ bcur, int M, int NB, int E, int* __restrict__ bstart) {
    __shared__ int sd[1024];
    int t = threadIdx.x;
    int v[4];
    int s = 0;
#pragma unroll
    for (int j = 0; j < 4; j++) {
        int i = t * 4 + j;
        v[j] = (i < M) ? bcur[i] : 0;
        s += v[j];
    }
    sd[t] = s;
    __syncthreads();
    for (int off = 1; off < 1024; off <<= 1) {
        int x = (t >= off) ? sd[t - off] : 0;
        __syncthreads();
        sd[t] += x;
        __syncthreads();
    }
    int run = (t == 0) ? 0 : sd[t - 1];
#pragma unroll
    for (int j = 0; j < 4; j++) {
        int i = t * 4 + j;
        if (i < M) bcur[i] = run;
        run += v[j];
    }
    __syncthreads();
    for (int b = t; b <= NB; b += 1024) bstart[b] = (b < NB) ? bcur[b * 8] : E;
}

// partition edges into (bucket,region)-ordered ebuf
__global__ __launch_bounds__(256) void k_part(const int* __restrict__ src, const int* __restrict__ dst,
                                              int E, int Er, int N, int* __restrict__ bcur,
                                              uint2* __restrict__ ebuf) {
    __shared__ int lcnt[391], lbase[391];
    const int NB = (N + 255) >> 8;
    int t = threadIdx.x;
    int r = blockIdx.x & 7, jb = blockIdx.x >> 3;
    int e0 = r * Er + jb * 4096;
    int e1 = min(min((r + 1) * Er, E), e0 + 4096);
    int s[16], d[16];
    for (int i = t; i < NB; i += 256) lcnt[i] = 0;
    __syncthreads();
#pragma unroll
    for (int j = 0; j < 16; j++) {
        int e = e0 + j * 256 + t;
        if (e < e1) {
            int dd = dst[e];
            dd = ((unsigned)dd < (unsigned)N) ? dd : 0;  // clamp: consistent everywhere
            d[j] = dd;
            s[j] = src[e];
            atomicAdd(&lcnt[dd >> 8], 1);
        } else d[j] = -1;
    }
    __syncthreads();
    for (int i = t; i < NB; i += 256)
        lbase[i] = lcnt[i] ? atomicAdd(&bcur[i * 8 + r], lcnt[i]) : 0;
    __syncthreads();
    for (int i = t; i < NB; i += 256) lcnt[i] = 0;
    __syncthreads();
#pragma unroll
    for (int j = 0; j < 16; j++) {
        if (d[j] >= 0) {
            int bk = d[j] >> 8;
            int pos = lbase[bk] + atomicAdd(&lcnt[bk], 1);
            ebuf[pos] = make_uint2((unsigned)s[j], (unsigned)d[j]);
        }
    }
}

// degree count: one block per bucket, LDS histogram, direct store (no global atomics)
__global__ __launch_bounds__(256) void k_degb(const uint2* __restrict__ ebuf,
                                              const int* __restrict__ bstart,
                                              int N, int* __restrict__ cnt) {
    __shared__ int h[256];
    int b = blockIdx.x;
    int base = b << 8;
    h[threadIdx.x] = 0;
    __syncthreads();
    int e0 = bstart[b], e1 = bstart[b + 1];
    for (int e = e0 + threadIdx.x; e < e1; e += 256)
        atomicAdd(&h[ebuf[e].y & 255], 1);
    __syncthreads();
    int n = base + threadIdx.x;
    if (n < N) cnt[n] = h[threadIdx.x];
}

// ---------------- exclusive scan of cnt -> offs (+ fused dinv) ----------------
__global__ void k_scan1(const int* __restrict__ cnt, int N,
                        int* __restrict__ offs, int* __restrict__ bsums,
                        float* __restrict__ dinv) {
    __shared__ int sd[256];
    int t = threadIdx.x;
    int base = blockIdx.x * 2048 + t * 8;
    int v[8];
    int s = 0;
#pragma unroll
    for (int j = 0; j < 8; j++) {
        int i = base + j;
        v[j] = (i < N) ? cnt[i] : 0;
        if (i < N) dinv[i] = rsqrtf((float)(v[j] + 1));  // +1 self-loop
        s += v[j];
    }
    sd[t] = s;
    __syncthreads();
    for (int off = 1; off < 256; off <<= 1) {
        int x = (t >= off) ? sd[t - off] : 0;
        __syncthreads();
        sd[t] += x;
        __syncthreads();
    }
    int excl = (t == 0) ? 0 : sd[t - 1];
    if (t == 255) bsums[blockIdx.x] = sd[255];
    int run = excl;
#pragma unroll
    for (int j = 0; j < 8; j++) {
        int i = base + j;
        if (i < N) offs[i] = run;
        run += v[j];
    }
}

__global__ void k_scan2(int* __restrict__ bsums, int nb) {  // nb <= 64, one wave
    int t = threadIdx.x;
    int v = (t < nb) ? bsums[t] : 0;
    int orig = v;
    for (int off = 1; off < 64; off <<= 1) {
        int y = __shfl_up(v, off);
        if (t >= off) v += y;
    }
    if (t < nb) bsums[t] = v - orig;  // exclusive
}

__global__ void k_scan3(int* __restrict__ offs, int N, const int* __restrict__ bsums) {
    int i = blockIdx.x * blockDim.x + threadIdx.x;
    if (i < N) offs[i] += bsums[i >> 11];
}

// CSR scatter: one block per bucket, LDS cursors + LDS offs cache.
// csr window (~16KB) written by exactly ONE block -> single-L2 ownership, full write merge.
__global__ __launch_bounds__(256) void k_scatb(const uint2* __restrict__ ebuf,
                                               const int* __restrict__ bstart,
                                               const int* __restrict__ offs,
                                               int N, int* __restrict__ csr) {
    __shared__ int lofs[256], lcur[256];
    int b = blockIdx.x;
    int base = b << 8;
    int n = base + threadIdx.x;
    lofs[threadIdx.x] = (n < N) ? offs[n] : 0;
    lcur[threadIdx.x] = 0;
    __syncthreads();
    int e0 = bstart[b], e1 = bstart[b + 1];
    for (int e = e0 + threadIdx.x; e < e1; e += 256) {
        uint2 p = ebuf[e];
        int ld = p.y & 255;
        int pos = atomicAdd(&lcur[ld], 1);
        csr[lofs[ld] + pos] = (int)p.x;
    }
}

// ---------------- X -> fp16 ----------------
__global__ __launch_bounds__(256) void k_xh(const float4* __restrict__ X4, int M,
                                            uint2* __restrict__ Xh) {
    int i = blockIdx.x * 256 + threadIdx.x;
    if (i < M) {
        float4 v = X4[i];
        __half2 lo = __floats2half2_rn(v.x, v.y);
        __half2 hi = __floats2half2_rn(v.z, v.w);
        uint2 o;
        o.x = *(unsigned*)&lo;
        o.y = *(unsigned*)&hi;
        Xh[i] = o;
    }
}

// ---------------- layer-1 aggregation (fp16 gather): aggXh[n] = fp16(dn*(dn*X[n] + sum ds*X[s])) ----------------
__global__ __launch_bounds__(256) void k_agg1(
        const uint2* __restrict__ Xh, const float* __restrict__ dinv,
        const int* __restrict__ offs, const int* __restrict__ cnt,
        const int* __restrict__ csr, int N, uint2* __restrict__ aggXh) {
    int tid = blockIdx.x * blockDim.x + threadIdx.x;
    int n = tid >> 4;
    int f = tid & 15;
    if (n >= N) return;
    float dn = dinv[n];
    float ax, ay, az, aw;
    {
        uint2 p = Xh[(size_t)n * 16 + f];
        __half2 lo = *(__half2*)&p.x, hi = *(__half2*)&p.y;
        ax = dn * __low2float(lo); ay = dn * __high2float(lo);
        az = dn * __low2float(hi); aw = dn * __high2float(hi);
    }
    int base = offs[n], deg = cnt[n];
    int j = 0;
    for (; j + 4 <= deg; j += 4) {
        int s0 = csr[base + j];
        int s1 = csr[base + j + 1];
        int s2 = csr[base + j + 2];
        int s3 = csr[base + j + 3];
        s0 = ((unsigned)s0 < (unsigned)N) ? s0 : 0;
        s1 = ((unsigned)s1 < (unsigned)N) ? s1 : 0;
        s2 = ((unsigned)s2 < (unsigned)N) ? s2 : 0;
        s3 = ((unsigned)s3 < (unsigned)N) ? s3 : 0;
        float w0 = dinv[s0], w1 = dinv[s1], w2 = dinv[s2], w3 = dinv[s3];
        uint2 p0 = Xh[(size_t)s0 * 16 + f];
        uint2 p1 = Xh[(size_t)s1 * 16 + f];
        uint2 p2 = Xh[(size_t)s2 * 16 + f];
        uint2 p3 = Xh[(size_t)s3 * 16 + f];
        __half2 l0 = *(__half2*)&p0.x, h0 = *(__half2*)&p0.y;
        __half2 l1 = *(__half2*)&p1.x, h1 = *(__half2*)&p1.y;
        __half2 l2 = *(__half2*)&p2.x, h2 = *(__half2*)&p2.y;
        __half2 l3 = *(__half2*)&p3.x, h3 = *(__half2*)&p3.y;
        ax += w0 * __low2float(l0) + w1 * __low2float(l1) + w2 * __low2float(l2) + w3 * __low2float(l3);
        ay += w0 * __high2float(l0) + w1 * __high2float(l1) + w2 * __high2float(l2) + w3 * __high2float(l3);
        az += w0 * __low2float(h0) + w1 * __low2float(h1) + w2 * __low2float(h2) + w3 * __low2float(h3);
        aw += w0 * __high2float(h0) + w1 * __high2float(h1) + w2 * __high2float(h2) + w3 * __high2float(h3);
    }
    for (; j < deg; j++) {
        int s0 = csr[base + j];
        s0 = ((unsigned)s0 < (unsigned)N) ? s0 : 0;
        float w0 = dinv[s0];
        uint2 p = Xh[(size_t)s0 * 16 + f];
        __half2 lo = *(__half2*)&p.x, hi = *(__half2*)&p.y;
        ax += w0 * __low2float(lo); ay += w0 * __high2float(lo);
        az += w0 * __low2float(hi); aw += w0 * __high2float(hi);
    }
    __half2 olo = __floats2half2_rn(dn * ax, dn * ay);
    __half2 ohi = __floats2half2_rn(dn * az, dn * aw);
    uint2 o;
    o.x = *(unsigned*)&olo;
    o.y = *(unsigned*)&ohi;
    aggXh[(size_t)n * 16 + f] = o;
}

// ---------------- MFMA MLP: h = elu(t@[Wn|Ws]+b); Zs = half(dn * h@Wf) ----------------
__global__ __launch_bounds__(256) void k_mlp(
        const _Float16* __restrict__ aggXh, const float* __restrict__ dinv,
        const float* __restrict__ Wn, const float* __restrict__ bn,
        const float* __restrict__ Ws, const float* __restrict__ bs,
        const float* __restrict__ Wf, int N, _Float16* __restrict__ Zs) {
    __shared__ half8 sB2[32 * 64];
    __shared__ _Float16 Hbuf[4][16 * 136];

    const int l = threadIdx.x & 63;
    const int wid = threadIdx.x >> 6;
    const int q = l >> 4;
    const int n16 = l & 15;

    for (int e = threadIdx.x; e < 32 * 64; e += 256) {
        int tile = e >> 6, le = e & 63;
        int kt = tile >> 2, nt = tile & 3;
        int qq = le >> 4, nn = le & 15;
        half8 v;
#pragma unroll
        for (int j = 0; j < 8; j++)
            v[j] = (_Float16)Wf[(kt * 32 + qq * 8 + j) * 64 + nt * 16 + nn];
        sB2[e] = v;
    }
    __syncthreads();

    half8 w1n[8], w1s[8];
#pragma unroll
    for (int nt = 0; nt < 8; nt++) {
        half8 a, b;
#pragma unroll
        for (int j = 0; j < 8; j++) {
            a[j] = (_Float16)Wn[(q * 8 + j) * 128 + nt * 16 + n16];
            b[j] = (_Float16)Ws[(q * 8 + j) * 128 + nt * 16 + n16];
        }
        w1n[nt] = a;
        w1s[nt] = b;
    }
    float bnr[8], bsr[8];
#pragma unroll
    for (int nt = 0; nt < 8; nt++) {
        bnr[nt] = bn[nt * 16 + n16];
        bsr[nt] = bs[nt * 16 + n16];
    }

    const int ntiles = (N + 15) >> 4;
    const int nw = gridDim.x * 4;
    _Float16* Hw = Hbuf[wid];

    for (int tile = blockIdx.x * 4 + wid; tile < ntiles; tile += nw) {
        int nb = tile << 4;
        int nodeA = nb + n16;
        if (nodeA >= N) nodeA = N - 1;
        float dn = dinv[nodeA];
        half8 an = *(const half8*)&aggXh[(size_t)nodeA * 64 + q * 8];
        half8 as = *(const half8*)&aggXh[(size_t)nodeA * 64 + 32 + q * 8];

        f32x4 Y[4];
#pragma unroll
        for (int i = 0; i < 4; i++) Y[i] = (f32x4){0.f, 0.f, 0.f, 0.f};

        f32x4 c1[8];
#pragma unroll
        for (int nt = 0; nt < 8; nt++)
            c1[nt] = __builtin_amdgcn_mfma_f32_16x16x32_f16(an, w1n[nt], (f32x4){0.f, 0.f, 0.f, 0.f}, 0, 0, 0);
#pragma unroll
        for (int nt = 0; nt < 8; nt++) {
#pragma unroll
            for (int r = 0; r < 4; r++) {
                float v = c1[nt][r] + bnr[nt];
                v = v > 0.f ? v : expm1f(v);
                Hw[(q * 4 + r) * 136 + nt * 16 + n16] = (_Float16)v;
            }
        }
#pragma unroll
        for (int kt = 0; kt < 4; kt++) {
            half8 ha = *(const half8*)&Hw[n16 * 136 + kt * 32 + q * 8];
#pragma unroll
            for (int nt2 = 0; nt2 < 4; nt2++)
                Y[nt2] = __builtin_amdgcn_mfma_f32_16x16x32_f16(ha, sB2[(kt * 4 + nt2) * 64 + l], Y[nt2], 0, 0, 0);
        }
#pragma unroll
        for (int nt = 0; nt < 8; nt++)
            c1[nt] = __builtin_amdgcn_mfma_f32_16x16x32_f16(as, w1s[nt], (f32x4){0.f, 0.f, 0.f, 0.f}, 0, 0, 0);
#pragma unroll
        for (int nt = 0; nt < 8; nt++) {
#pragma unroll
            for (int r = 0; r < 4; r++) {
                float v = c1[nt][r] + bsr[nt];
                v = v > 0.f ? v : expm1f(v);
                Hw[(q * 4 + r) * 136 + nt * 16 + n16] = (_Float16)v;
            }
        }
#pragma unroll
        for (int kt = 0; kt < 4; kt++) {
            half8 ha = *(const half8*)&Hw[n16 * 136 + kt * 32 + q * 8];
#pragma unroll
            for (int nt2 = 0; nt2 < 4; nt2++)
                Y[nt2] = __builtin_amdgcn_mfma_f32_16x16x32_f16(ha, sB2[((4 + kt) * 4 + nt2) * 64 + l], Y[nt2], 0, 0, 0);
        }
        float dnr[4];
#pragma unroll
        for (int r = 0; r < 4; r++) dnr[r] = __shfl(dn, q * 4 + r);
#pragma unroll
        for (int r = 0; r < 4; r++) {
            int node = nb + q * 4 + r;
            if (node < N) {
#pragma unroll
                for (int nt2 = 0; nt2 < 4; nt2++)
                    Zs[(size_t)node * 64 + nt2 * 16 + n16] = (_Float16)(dnr[r] * Y[nt2][r]);
            }
        }
    }
}

// ---------------- layer-2 aggregation + bias + softmax ----------------
__global__ __launch_bounds__(256) void k_agg2(
        const uint2* __restrict__ Zu, const float* __restrict__ dinv,
        const int* __restrict__ offs, const int* __restrict__ cnt,
        const int* __restrict__ csr, const float4* __restrict__ bias4,
        int N, float4* __restrict__ out4) {
    int tid = blockIdx.x * blockDim.x + threadIdx.x;
    int n = tid >> 4;
    int f = tid & 15;
    if (n >= N) return;
    float ax = 0.f, ay = 0.f, az = 0.f, aw = 0.f;
    {
        uint2 p = Zu[(size_t)n * 16 + f];
        __half2 lo = *(__half2*)&p.x, hi = *(__half2*)&p.y;
        ax = __low2float(lo); ay = __high2float(lo);
        az = __low2float(hi); aw = __high2float(hi);
    }
    int base = offs[n], deg = cnt[n];
    int j = 0;
    for (; j + 4 <= deg; j += 4) {
        int s0 = csr[base + j];
        int s1 = csr[base + j + 1];
        int s2 = csr[base + j + 2];
        int s3 = csr[base + j + 3];
        s0 = ((unsigned)s0 < (unsigned)N) ? s0 : 0;
        s1 = ((unsigned)s1 < (unsigned)N) ? s1 : 0;
        s2 = ((unsigned)s2 < (unsigned)N) ? s2 : 0;
        s3 = ((unsigned)s3 < (unsigned)N) ? s3 : 0;
        uint2 p0 = Zu[(size_t)s0 * 16 + f];
        uint2 p1 = Zu[(size_t)s1 * 16 + f];
        uint2 p2 = Zu[(size_t)s2 * 16 + f];
        uint2 p3 = Zu[(size_t)s3 * 16 + f];
#pragma unroll
        for (int k = 0; k < 4; k++) {
            uint2 p = (k == 0) ? p0 : (k == 1) ? p1 : (k == 2) ? p2 : p3;
            __half2 lo = *(__half2*)&p.x, hi = *(__half2*)&p.y;
            ax += __low2float(lo); ay += __high2float(lo);
            az += __low2float(hi); aw += __high2float(hi);
        }
    }
    for (; j < deg; j++) {
        int s0 = csr[base + j];
        s0 = ((unsigned)s0 < (unsigned)N) ? s0 : 0;
        uint2 p = Zu[(size_t)s0 * 16 + f];
        __half2 lo = *(__half2*)&p.x, hi = *(__half2*)&p.y;
        ax += __low2float(lo); ay += __high2float(lo);
        az += __low2float(hi); aw += __high2float(hi);
    }
    float dn = dinv[n];
    float4 b = bias4[f];
    ax = dn * ax + b.x; ay = dn * ay + b.y; az = dn * az + b.z; aw = dn * aw + b.w;
    float mx = fmaxf(fmaxf(ax, ay), fmaxf(az, aw));
    for (int o = 8; o >= 1; o >>= 1) mx = fmaxf(mx, __shfl_xor(mx, o));
    float ex = expf(ax - mx), ey = expf(ay - mx), ez = expf(az - mx), ew = expf(aw - mx);
    float sm = ex + ey + ez + ew;
    for (int o = 8; o >= 1; o >>= 1) sm += __shfl_xor(sm, o);
    float inv = 1.f / sm;
    out4[(size_t)n * 16 + f] = make_float4(ex * inv, ey * inv, ez * inv, ew * inv);
}

extern "C" void kernel_launch(void* const* d_in, const int* in_sizes, int n_in,
                              void* d_out, int out_size, void* d_ws, size_t ws_size,
                              hipStream_t stream) {
    const float* X = (const float*)d_in[0];
    const int* ei = (const int*)d_in[1];
    // d_in[2] = batch (unused)
    const float* Wn = (const float*)d_in[3];
    const float* bn = (const float*)d_in[4];
    const float* Ws = (const float*)d_in[5];
    const float* bs = (const float*)d_in[6];
    const float* Wf = (const float*)d_in[7];
    const float* bfu = (const float*)d_in[8];

    const int N = in_sizes[2];        // 100000
    const int E = in_sizes[1] / 2;    // 1600000
    const int* src = ei;
    const int* dst = ei + E;
    const int NB = (N + 255) >> 8;    // 391 buckets

    // workspace layout (128-aligned); total ~33.2 MB
    char* ws = (char*)d_ws;
    int* bcur     = (int*)(ws + 0);            // NB*8*4 = 12512 -> pad 12800
    int* bstart   = (int*)(ws + 12800);        // (NB+1)*4 -> pad 14464
    int* cnt      = (int*)(ws + 14464);        // 400000 -> 414464
    float* dinv   = (float*)(ws + 414464);     // 400000 -> 814464
    int* offs     = (int*)(ws + 814464);       // 400000 -> 1214464
    int* bsums    = (int*)(ws + 1214464);      // 256    -> 1214720
    int* csr      = (int*)(ws + 1214720);      // 6400000 -> 7614720
    // slot A: ebuf (part/degb/scatb), then aggXh (agg1 -> mlp)
    uint2* ebuf   = (uint2*)(ws + 7614720);    // 12800000 -> 20414720
    uint2* aggXh  = (uint2*)(ws + 7614720);
    // slot B: Xh (xh -> agg1), then Zs (mlp -> agg2)
    uint2* Xh     = (uint2*)(ws + 20414720);   // 12800000 -> 33214720 total
    _Float16* Zs  = (_Float16*)(ws + 20414720);

    hipMemsetAsync(ws, 0, 12800, stream);  // zero bcur only

    int nbl = (N + 255) / 256;
    int nb1 = (N + 2047) / 2048;          // 49 <= 64
    int Er = (E + 7) / 8;                 // edges per region
    int sbl = 8 * ((Er + 4095) / 4096);   // swizzled grid for bhist/part

    k_bhist<<<sbl, 256, NB * 4, stream>>>(dst, E, Er, N, bcur);
    k_bscan<<<1, 1024, 0, stream>>>(bcur, NB * 8, NB, E, bstart);
    k_part<<<sbl, 256, 0, stream>>>(src, dst, E, Er, N, bcur, ebuf);
    k_degb<<<NB, 256, 0, stream>>>(ebuf, bstart, N, cnt);
    k_scan1<<<nb1, 256, 0, stream>>>(cnt, N, offs, bsums, dinv);
    k_scan2<<<1, 64, 0, stream>>>(bsums, nb1);
    k_scan3<<<nbl, 256, 0, stream>>>(offs, N, bsums);
    k_scatb<<<NB, 256, 0, stream>>>(ebuf, bstart, offs, N, csr);

    int M = N * 16;
    k_xh<<<(M + 255) / 256, 256, 0, stream>>>((const float4*)X, M, Xh);

    int gbl = (M + 255) / 256;  // thread-per-(node, chunk)
    k_agg1<<<gbl, 256, 0, stream>>>(Xh, dinv, offs, cnt, csr, N, aggXh);
    k_mlp<<<512, 256, 0, stream>>>((const _Float16*)aggXh, dinv, Wn, bn, Ws, bs, Wf, N, Zs);
    k_agg2<<<gbl, 256, 0, stream>>>((const uint2*)Zs, dinv, offs, cnt, csr,
                                    (const float4*)bfu, N, (float4*)d_out);
}

// Round 10
// 258.404 us; speedup vs baseline: 4.2741x; 1.0247x over previous
//
#include <hip/hip_runtime.h>
#include <hip/hip_fp16.h>

using half8 = __attribute__((ext_vector_type(8))) _Float16;
using f32x4 = __attribute__((ext_vector_type(4))) float;

// ============ bucketed CSR build ============
// bucket b = dst >> 8 (256 nodes/bucket, NB=391); region r = blockIdx%8 edge slice.
// ebuf order: bucket-major, region-minor. One block later owns one whole bucket.

__global__ __launch_bounds__(256) void k_bhist(const int* __restrict__ dst, int E, int Er, int N,
                                               int* __restrict__ bhist) {
    extern __shared__ int h[];  // NB ints
    const int NB = (N + 255) >> 8;
    for (int i = threadIdx.x; i < NB; i += 256) h[i] = 0;
    __syncthreads();
    int r = blockIdx.x & 7, j = blockIdx.x >> 3;
    int e0 = r * Er + j * 4096;
    int e1 = min(min((r + 1) * Er, E), e0 + 4096);
    for (int e = e0 + threadIdx.x; e < e1; e += 256) {
        int d = dst[e];
        d = ((unsigned)d < (unsigned)N) ? d : 0;
        atomicAdd(&h[d >> 8], 1);
    }
    __syncthreads();
    for (int i = threadIdx.x; i < NB; i += 256)
        if (h[i]) atomicAdd(&bhist[i * 8 + r], h[i]);
}

// exclusive scan of bcur[M], M = NB*8 <= 4096; also emit pristine bucket starts
__global__ void k_bscan(int* __restrict__ bcur, int M, int NB, int E, int* __restrict__ bstart) {
    __shared__ int sd[1024];
    int t = threadIdx.x;
    int v[4];
    int s = 0;
#pragma unroll
    for (int j = 0; j < 4; j++) {
        int i = t * 4 + j;
        v[j] = (i < M) ? bcur[i] : 0;
        s += v[j];
    }
    sd[t] = s;
    __syncthreads();
    for (int off = 1; off < 1024; off <<= 1) {
        int x = (t >= off) ? sd[t - off] : 0;
        __syncthreads();
        sd[t] += x;
        __syncthreads();
    }
    int run = (t == 0) ? 0 : sd[t - 1];
#pragma unroll
    for (int j = 0; j < 4; j++) {
        int i = t * 4 + j;
        if (i < M) bcur[i] = run;
        run += v[j];
    }
    __syncthreads();
    for (int b = t; b <= NB; b += 1024) bstart[b] = (b < NB) ? bcur[b * 8] : E;
}

// partition edges into (bucket,region)-ordered ebuf; tail: fused X->fp16 conversion
__global__ __launch_bounds__(256) void k_part(const int* __restrict__ src, const int* __restrict__ dst,
                                              int E, int Er, int N, int* __restrict__ bcur,
                                              uint2* __restrict__ ebuf,
                                              const float4* __restrict__ X4, int M,
                                              uint2* __restrict__ Xh) {
    __shared__ int lcnt[391], lbase[391];
    const int NB = (N + 255) >> 8;
    int t = threadIdx.x;
    int r = blockIdx.x & 7, jb = blockIdx.x >> 3;
    int e0 = r * Er + jb * 4096;
    int e1 = min(min((r + 1) * Er, E), e0 + 4096);
    int s[16], d[16];
    for (int i = t; i < NB; i += 256) lcnt[i] = 0;
    __syncthreads();
#pragma unroll
    for (int j = 0; j < 16; j++) {
        int e = e0 + j * 256 + t;
        if (e < e1) {
            int dd = dst[e];
            dd = ((unsigned)dd < (unsigned)N) ? dd : 0;  // clamp: consistent everywhere
            d[j] = dd;
            s[j] = src[e];
            atomicAdd(&lcnt[dd >> 8], 1);
        } else d[j] = -1;
    }
    __syncthreads();
    for (int i = t; i < NB; i += 256)
        lbase[i] = lcnt[i] ? atomicAdd(&bcur[i * 8 + r], lcnt[i]) : 0;
    __syncthreads();
    for (int i = t; i < NB; i += 256) lcnt[i] = 0;
    __syncthreads();
#pragma unroll
    for (int j = 0; j < 16; j++) {
        if (d[j] >= 0) {
            int bk = d[j] >> 8;
            int pos = lbase[bk] + atomicAdd(&lcnt[bk], 1);
            ebuf[pos] = make_uint2((unsigned)s[j], (unsigned)d[j]);
        }
    }
    // fused X -> fp16 streaming conversion (independent work; fills latency bubbles)
    for (int i = blockIdx.x * 256 + t; i < M; i += gridDim.x * 256) {
        float4 v = X4[i];
        __half2 lo = __floats2half2_rn(v.x, v.y);
        __half2 hi = __floats2half2_rn(v.z, v.w);
        uint2 o;
        o.x = *(unsigned*)&lo;
        o.y = *(unsigned*)&hi;
        Xh[i] = o;
    }
}

// one block per bucket: LDS degree hist -> local scan (global offs = bstart[b] + local prefix,
// NO global scan needed) -> write cnt/offs/dinv -> LDS-cursor CSR scatter (single-L2 window).
__global__ __launch_bounds__(256) void k_build(const uint2* __restrict__ ebuf,
                                               const int* __restrict__ bstart, int N,
                                               int* __restrict__ cnt, float* __restrict__ dinv,
                                               int* __restrict__ offs, int* __restrict__ csr) {
    __shared__ int h[256], sc[256], lcur[256];
    int b = blockIdx.x, t = threadIdx.x;
    int base = b << 8;
    h[t] = 0;
    __syncthreads();
    int e0 = bstart[b], e1 = bstart[b + 1];
    for (int e = e0 + t; e < e1; e += 256)
        atomicAdd(&h[ebuf[e].y & 255], 1);
    __syncthreads();
    int v = h[t];
    sc[t] = v;
    __syncthreads();
    for (int off = 1; off < 256; off <<= 1) {
        int x = (t >= off) ? sc[t - off] : 0;
        __syncthreads();
        sc[t] += x;
        __syncthreads();
    }
    int lo = e0 + sc[t] - v;  // global csr offset for node base+t
    int n = base + t;
    if (n < N) {
        cnt[n] = v;
        offs[n] = lo;
        dinv[n] = rsqrtf((float)(v + 1));  // +1 self-loop
    }
    lcur[t] = 0;
    sc[t] = lo;  // reuse as lofs (own-entry write after own-entry read: race-free)
    __syncthreads();
    for (int e = e0 + t; e < e1; e += 256) {
        uint2 p = ebuf[e];
        int ld = p.y & 255;
        int pos = atomicAdd(&lcur[ld], 1);
        csr[sc[ld] + pos] = (int)p.x;
    }
}

// ---------------- layer-1 aggregation (fp16 gather): aggXh[n] = fp16(dn*(dn*X[n] + sum ds*X[s])) ----------------
__global__ __launch_bounds__(256) void k_agg1(
        const uint2* __restrict__ Xh, const float* __restrict__ dinv,
        const int* __restrict__ offs, const int* __restrict__ cnt,
        const int* __restrict__ csr, int N, uint2* __restrict__ aggXh) {
    int tid = blockIdx.x * blockDim.x + threadIdx.x;
    int n = tid >> 4;
    int f = tid & 15;
    if (n >= N) return;
    float dn = dinv[n];
    float ax, ay, az, aw;
    {
        uint2 p = Xh[(size_t)n * 16 + f];
        __half2 lo = *(__half2*)&p.x, hi = *(__half2*)&p.y;
        ax = dn * __low2float(lo); ay = dn * __high2float(lo);
        az = dn * __low2float(hi); aw = dn * __high2float(hi);
    }
    int base = offs[n], deg = cnt[n];
    int j = 0;
    for (; j + 4 <= deg; j += 4) {
        int s0 = csr[base + j];
        int s1 = csr[base + j + 1];
        int s2 = csr[base + j + 2];
        int s3 = csr[base + j + 3];
        s0 = ((unsigned)s0 < (unsigned)N) ? s0 : 0;
        s1 = ((unsigned)s1 < (unsigned)N) ? s1 : 0;
        s2 = ((unsigned)s2 < (unsigned)N) ? s2 : 0;
        s3 = ((unsigned)s3 < (unsigned)N) ? s3 : 0;
        float w0 = dinv[s0], w1 = dinv[s1], w2 = dinv[s2], w3 = dinv[s3];
        uint2 p0 = Xh[(size_t)s0 * 16 + f];
        uint2 p1 = Xh[(size_t)s1 * 16 + f];
        uint2 p2 = Xh[(size_t)s2 * 16 + f];
        uint2 p3 = Xh[(size_t)s3 * 16 + f];
        __half2 l0 = *(__half2*)&p0.x, h0 = *(__half2*)&p0.y;
        __half2 l1 = *(__half2*)&p1.x, h1 = *(__half2*)&p1.y;
        __half2 l2 = *(__half2*)&p2.x, h2 = *(__half2*)&p2.y;
        __half2 l3 = *(__half2*)&p3.x, h3 = *(__half2*)&p3.y;
        ax += w0 * __low2float(l0) + w1 * __low2float(l1) + w2 * __low2float(l2) + w3 * __low2float(l3);
        ay += w0 * __high2float(l0) + w1 * __high2float(l1) + w2 * __high2float(l2) + w3 * __high2float(l3);
        az += w0 * __low2float(h0) + w1 * __low2float(h1) + w2 * __low2float(h2) + w3 * __low2float(h3);
        aw += w0 * __high2float(h0) + w1 * __high2float(h1) + w2 * __high2float(h2) + w3 * __high2float(h3);
    }
    for (; j < deg; j++) {
        int s0 = csr[base + j];
        s0 = ((unsigned)s0 < (unsigned)N) ? s0 : 0;
        float w0 = dinv[s0];
        uint2 p = Xh[(size_t)s0 * 16 + f];
        __half2 lo = *(__half2*)&p.x, hi = *(__half2*)&p.y;
        ax += w0 * __low2float(lo); ay += w0 * __high2float(lo);
        az += w0 * __low2float(hi); aw += w0 * __high2float(hi);
    }
    __half2 olo = __floats2half2_rn(dn * ax, dn * ay);
    __half2 ohi = __floats2half2_rn(dn * az, dn * aw);
    uint2 o;
    o.x = *(unsigned*)&olo;
    o.y = *(unsigned*)&ohi;
    aggXh[(size_t)n * 16 + f] = o;
}

// ---------------- MFMA MLP: h = elu(t@[Wn|Ws]+b); Zs = half(dn * h@Wf) ----------------
__global__ __launch_bounds__(256) void k_mlp(
        const _Float16* __restrict__ aggXh, const float* __restrict__ dinv,
        const float* __restrict__ Wn, const float* __restrict__ bn,
        const float* __restrict__ Ws, const float* __restrict__ bs,
        const float* __restrict__ Wf, int N, _Float16* __restrict__ Zs) {
    __shared__ half8 sB2[32 * 64];
    __shared__ _Float16 Hbuf[4][16 * 136];

    const int l = threadIdx.x & 63;
    const int wid = threadIdx.x >> 6;
    const int q = l >> 4;
    const int n16 = l & 15;

    for (int e = threadIdx.x; e < 32 * 64; e += 256) {
        int tile = e >> 6, le = e & 63;
        int kt = tile >> 2, nt = tile & 3;
        int qq = le >> 4, nn = le & 15;
        half8 v;
#pragma unroll
        for (int j = 0; j < 8; j++)
            v[j] = (_Float16)Wf[(kt * 32 + qq * 8 + j) * 64 + nt * 16 + nn];
        sB2[e] = v;
    }
    __syncthreads();

    half8 w1n[8], w1s[8];
#pragma unroll
    for (int nt = 0; nt < 8; nt++) {
        half8 a, b;
#pragma unroll
        for (int j = 0; j < 8; j++) {
            a[j] = (_Float16)Wn[(q * 8 + j) * 128 + nt * 16 + n16];
            b[j] = (_Float16)Ws[(q * 8 + j) * 128 + nt * 16 + n16];
        }
        w1n[nt] = a;
        w1s[nt] = b;
    }
    float bnr[8], bsr[8];
#pragma unroll
    for (int nt = 0; nt < 8; nt++) {
        bnr[nt] = bn[nt * 16 + n16];
        bsr[nt] = bs[nt * 16 + n16];
    }

    const int ntiles = (N + 15) >> 4;
    const int nw = gridDim.x * 4;
    _Float16* Hw = Hbuf[wid];

    for (int tile = blockIdx.x * 4 + wid; tile < ntiles; tile += nw) {
        int nb = tile << 4;
        int nodeA = nb + n16;
        if (nodeA >= N) nodeA = N - 1;
        float dn = dinv[nodeA];
        half8 an = *(const half8*)&aggXh[(size_t)nodeA * 64 + q * 8];
        half8 as = *(const half8*)&aggXh[(size_t)nodeA * 64 + 32 + q * 8];

        f32x4 Y[4];
#pragma unroll
        for (int i = 0; i < 4; i++) Y[i] = (f32x4){0.f, 0.f, 0.f, 0.f};

        f32x4 c1[8];
#pragma unroll
        for (int nt = 0; nt < 8; nt++)
            c1[nt] = __builtin_amdgcn_mfma_f32_16x16x32_f16(an, w1n[nt], (f32x4){0.f, 0.f, 0.f, 0.f}, 0, 0, 0);
#pragma unroll
        for (int nt = 0; nt < 8; nt++) {
#pragma unroll
            for (int r = 0; r < 4; r++) {
                float v = c1[nt][r] + bnr[nt];
                v = v > 0.f ? v : expm1f(v);
                Hw[(q * 4 + r) * 136 + nt * 16 + n16] = (_Float16)v;
            }
        }
#pragma unroll
        for (int kt = 0; kt < 4; kt++) {
            half8 ha = *(const half8*)&Hw[n16 * 136 + kt * 32 + q * 8];
#pragma unroll
            for (int nt2 = 0; nt2 < 4; nt2++)
                Y[nt2] = __builtin_amdgcn_mfma_f32_16x16x32_f16(ha, sB2[(kt * 4 + nt2) * 64 + l], Y[nt2], 0, 0, 0);
        }
#pragma unroll
        for (int nt = 0; nt < 8; nt++)
            c1[nt] = __builtin_amdgcn_mfma_f32_16x16x32_f16(as, w1s[nt], (f32x4){0.f, 0.f, 0.f, 0.f}, 0, 0, 0);
#pragma unroll
        for (int nt = 0; nt < 8; nt++) {
#pragma unroll
            for (int r = 0; r < 4; r++) {
                float v = c1[nt][r] + bsr[nt];
                v = v > 0.f ? v : expm1f(v);
                Hw[(q * 4 + r) * 136 + nt * 16 + n16] = (_Float16)v;
            }
        }
#pragma unroll
        for (int kt = 0; kt < 4; kt++) {
            half8 ha = *(const half8*)&Hw[n16 * 136 + kt * 32 + q * 8];
#pragma unroll
            for (int nt2 = 0; nt2 < 4; nt2++)
                Y[nt2] = __builtin_amdgcn_mfma_f32_16x16x32_f16(ha, sB2[((4 + kt) * 4 + nt2) * 64 + l], Y[nt2], 0, 0, 0);
        }
        float dnr[4];
#pragma unroll
        for (int r = 0; r < 4; r++) dnr[r] = __shfl(dn, q * 4 + r);
#pragma unroll
        for (int r = 0; r < 4; r++) {
            int node = nb + q * 4 + r;
            if (node < N) {
#pragma unroll
                for (int nt2 = 0; nt2 < 4; nt2++)
                    Zs[(size_t)node * 64 + nt2 * 16 + n16] = (_Float16)(dnr[r] * Y[nt2][r]);
            }
        }
    }
}

// ---------------- layer-2 aggregation + bias + softmax ----------------
__global__ __launch_bounds__(256) void k_agg2(
        const uint2* __restrict__ Zu, const float* __restrict__ dinv,
        const int* __restrict__ offs, const int* __restrict__ cnt,
        const int* __restrict__ csr, const float4* __restrict__ bias4,
        int N, float4* __restrict__ out4) {
    int tid = blockIdx.x * blockDim.x + threadIdx.x;
    int n = tid >> 4;
    int f = tid & 15;
    if (n >= N) return;
    float ax = 0.f, ay = 0.f, az = 0.f, aw = 0.f;
    {
        uint2 p = Zu[(size_t)n * 16 + f];
        __half2 lo = *(__half2*)&p.x, hi = *(__half2*)&p.y;
        ax = __low2float(lo); ay = __high2float(lo);
        az = __low2float(hi); aw = __high2float(hi);
    }
    int base = offs[n], deg = cnt[n];
    int j = 0;
    for (; j + 4 <= deg; j += 4) {
        int s0 = csr[base + j];
        int s1 = csr[base + j + 1];
        int s2 = csr[base + j + 2];
        int s3 = csr[base + j + 3];
        s0 = ((unsigned)s0 < (unsigned)N) ? s0 : 0;
        s1 = ((unsigned)s1 < (unsigned)N) ? s1 : 0;
        s2 = ((unsigned)s2 < (unsigned)N) ? s2 : 0;
        s3 = ((unsigned)s3 < (unsigned)N) ? s3 : 0;
        uint2 p0 = Zu[(size_t)s0 * 16 + f];
        uint2 p1 = Zu[(size_t)s1 * 16 + f];
        uint2 p2 = Zu[(size_t)s2 * 16 + f];
        uint2 p3 = Zu[(size_t)s3 * 16 + f];
#pragma unroll
        for (int k = 0; k < 4; k++) {
            uint2 p = (k == 0) ? p0 : (k == 1) ? p1 : (k == 2) ? p2 : p3;
            __half2 lo = *(__half2*)&p.x, hi = *(__half2*)&p.y;
            ax += __low2float(lo); ay += __high2float(lo);
            az += __low2float(hi); aw += __high2float(hi);
        }
    }
    for (; j < deg; j++) {
        int s0 = csr[base + j];
        s0 = ((unsigned)s0 < (unsigned)N) ? s0 : 0;
        uint2 p = Zu[(size_t)s0 * 16 + f];
        __half2 lo = *(__half2*)&p.x, hi = *(__half2*)&p.y;
        ax += __low2float(lo); ay += __high2float(lo);
        az += __low2float(hi); aw += __high2float(hi);
    }
    float dn = dinv[n];
    float4 b = bias4[f];
    ax = dn * ax + b.x; ay = dn * ay + b.y; az = dn * az + b.z; aw = dn * aw + b.w;
    float mx = fmaxf(fmaxf(ax, ay), fmaxf(az, aw));
    for (int o = 8; o >= 1; o >>= 1) mx = fmaxf(mx, __shfl_xor(mx, o));
    float ex = expf(ax - mx), ey = expf(ay - mx), ez = expf(az - mx), ew = expf(aw - mx);
    float sm = ex + ey + ez + ew;
    for (int o = 8; o >= 1; o >>= 1) sm += __shfl_xor(sm, o);
    float inv = 1.f / sm;
    out4[(size_t)n * 16 + f] = make_float4(ex * inv, ey * inv, ez * inv, ew * inv);
}

extern "C" void kernel_launch(void* const* d_in, const int* in_sizes, int n_in,
                              void* d_out, int out_size, void* d_ws, size_t ws_size,
                              hipStream_t stream) {
    const float* X = (const float*)d_in[0];
    const int* ei = (const int*)d_in[1];
    // d_in[2] = batch (unused)
    const float* Wn = (const float*)d_in[3];
    const float* bn = (const float*)d_in[4];
    const float* Ws = (const float*)d_in[5];
    const float* bs = (const float*)d_in[6];
    const float* Wf = (const float*)d_in[7];
    const float* bfu = (const float*)d_in[8];

    const int N = in_sizes[2];        // 100000
    const int E = in_sizes[1] / 2;    // 1600000
    const int* src = ei;
    const int* dst = ei + E;
    const int NB = (N + 255) >> 8;    // 391 buckets

    // workspace layout (128-aligned); total ~33.2 MB
    char* ws = (char*)d_ws;
    int* bcur     = (int*)(ws + 0);            // NB*8*4 = 12512 -> pad 12800
    int* bstart   = (int*)(ws + 12800);        // (NB+1)*4 -> pad 14464
    int* cnt      = (int*)(ws + 14464);        // 400000 -> 414464
    float* dinv   = (float*)(ws + 414464);     // 400000 -> 814464
    int* offs     = (int*)(ws + 814464);       // 400000 -> 1214464
    int* csr      = (int*)(ws + 1214464);      // 6400000 -> 7614464
    // slot A: ebuf (part/build), then aggXh (agg1 -> mlp)
    uint2* ebuf   = (uint2*)(ws + 7614464);    // 12800000 -> 20414464
    uint2* aggXh  = (uint2*)(ws + 7614464);
    // slot B: Xh (part-tail -> agg1), then Zs (mlp -> agg2)
    uint2* Xh     = (uint2*)(ws + 20414464);   // 12800000 -> 33214464 total
    _Float16* Zs  = (_Float16*)(ws + 20414464);

    hipMemsetAsync(ws, 0, 12800, stream);  // zero bcur only

    int Er = (E + 7) / 8;                 // edges per region
    int sbl = 8 * ((Er + 4095) / 4096);   // swizzled grid for bhist/part
    int M = N * 16;

    k_bhist<<<sbl, 256, NB * 4, stream>>>(dst, E, Er, N, bcur);
    k_bscan<<<1, 1024, 0, stream>>>(bcur, NB * 8, NB, E, bstart);
    k_part<<<sbl, 256, 0, stream>>>(src, dst, E, Er, N, bcur, ebuf, (const float4*)X, M, Xh);
    k_build<<<NB, 256, 0, stream>>>(ebuf, bstart, N, cnt, dinv, offs, csr);

    int gbl = (M + 255) / 256;  // thread-per-(node, chunk)
    k_agg1<<<gbl, 256, 0, stream>>>(Xh, dinv, offs, cnt, csr, N, aggXh);
    k_mlp<<<512, 256, 0, stream>>>((const _Float16*)aggXh, dinv, Wn, bn, Ws, bs, Wf, N, Zs);
    k_agg2<<<gbl, 256, 0, stream>>>((const uint2*)Zs, dinv, offs, cnt, csr,
                                    (const float4*)bfu, N, (float4*)d_out);
}